// Round 4
// baseline (11653.147 us; speedup 1.0000x reference)
//
#include <hip/hip_runtime.h>

// Problem constants
#define LL   8
#define HH   4
#define QQ   64
#define DD   512
#define NN   2048
#define DFFC 2048
#define ENTRY_CAP (1 << 18)

// ---------------------------------------------------------------------------
// Generic fp32 tiled GEMM: C = op(A) @ op(B) (+bias per COLUMN)(+relu)(+res)
//   TRANSA=0: A stored [M,K] ld=lda.  TRANSA=1: A stored [K,M] (C = A^T B).
//   TRANSB=0: B stored [K,N] ld=ldb.  TRANSB=1: B stored [N,K] (op(B)=B^T).
//   C is [M,N] ld=ldc row-major. res same layout as C. bias indexed by col.
//   Batched via blockIdx.z with strides sA/sB/sC (0 => shared operand).
//   64x64 tile, BK=16, 256 threads, 4x4 per thread.  (unchanged from R2-pass)
// ---------------------------------------------------------------------------
template <int TRANSA, int TRANSB, int RELU>
__global__ __launch_bounds__(256) void gemm_k(
    const float* __restrict__ A, const float* __restrict__ B,
    float* __restrict__ C, const float* __restrict__ bias,
    const float* __restrict__ res, int M, int N, int K,
    int lda, int ldb, int ldc, long sA, long sB, long sC)
{
    int bz = blockIdx.z;
    A += bz * sA;
    B += bz * sB;
    C += bz * sC;

    __shared__ float As[16][68];
    __shared__ float Bs[16][68];

    const int tid = threadIdx.x;
    const int tx = tid & 15;
    const int ty = tid >> 4;
    const int rowBase = blockIdx.y * 64;
    const int colBase = blockIdx.x * 64;

    float acc[4][4] = {};

    for (int k0 = 0; k0 < K; k0 += 16) {
        if (TRANSA) {
            int m = tid & 63, kk = tid >> 6;
#pragma unroll
            for (int p = 0; p < 4; p++)
                As[kk + 4 * p][m] = A[(long)(k0 + kk + 4 * p) * lda + rowBase + m];
        } else {
            int kk = tid & 15, mm = tid >> 4;
#pragma unroll
            for (int p = 0; p < 4; p++)
                As[kk][mm + 16 * p] = A[(long)(rowBase + mm + 16 * p) * lda + k0 + kk];
        }
        if (TRANSB) {
            int kk = tid & 15, nn = tid >> 4;
#pragma unroll
            for (int p = 0; p < 4; p++)
                Bs[kk][nn + 16 * p] = B[(long)(colBase + nn + 16 * p) * ldb + k0 + kk];
        } else {
            int n = tid & 63, kk = tid >> 6;
#pragma unroll
            for (int p = 0; p < 4; p++)
                Bs[kk + 4 * p][n] = B[(long)(k0 + kk + 4 * p) * ldb + colBase + n];
        }
        __syncthreads();

#pragma unroll
        for (int kk = 0; kk < 16; kk++) {
            float a0 = As[kk][ty * 4 + 0];
            float a1 = As[kk][ty * 4 + 1];
            float a2 = As[kk][ty * 4 + 2];
            float a3 = As[kk][ty * 4 + 3];
            float b0 = Bs[kk][tx * 4 + 0];
            float b1 = Bs[kk][tx * 4 + 1];
            float b2 = Bs[kk][tx * 4 + 2];
            float b3 = Bs[kk][tx * 4 + 3];
            acc[0][0] += a0 * b0; acc[0][1] += a0 * b1; acc[0][2] += a0 * b2; acc[0][3] += a0 * b3;
            acc[1][0] += a1 * b0; acc[1][1] += a1 * b1; acc[1][2] += a1 * b2; acc[1][3] += a1 * b3;
            acc[2][0] += a2 * b0; acc[2][1] += a2 * b1; acc[2][2] += a2 * b2; acc[2][3] += a2 * b3;
            acc[3][0] += a3 * b0; acc[3][1] += a3 * b1; acc[3][2] += a3 * b2; acc[3][3] += a3 * b3;
        }
        __syncthreads();
    }

#pragma unroll
    for (int i = 0; i < 4; i++) {
        int r = rowBase + ty * 4 + i;
#pragma unroll
        for (int j = 0; j < 4; j++) {
            int c = colBase + tx * 4 + j;
            float v = acc[i][j];
            if (bias) v += bias[c];
            if (RELU) v = fmaxf(v, 0.0f);
            if (res) v += res[(long)r * ldc + c];
            C[(long)r * ldc + c] = v;
        }
    }
}

// ---------------------------------------------------------------------------
// zero: per-layer counter reset (cntM[2048] + the flat-entry counter).
// ---------------------------------------------------------------------------
__global__ __launch_bounds__(256) void zero_k(int* __restrict__ cntM,
                                              int* __restrict__ counter)
{
    int i = blockIdx.x * 256 + threadIdx.x;
    cntM[i] = 0;
    if (i == 0) *counter = 0;
}

// ---------------------------------------------------------------------------
// extract: one wave per score row (h,n). Computes rowmax, count, wrecip and
// emits flat packed entries (row<<11 | m) PLUS per-column counts cntM[m].
// cntM is incremented only for entries actually stored (cap-consistent).
// S is [H*NN, NN] row-major.
// ---------------------------------------------------------------------------
__global__ __launch_bounds__(256) void extract_k(
    const float* __restrict__ S, float* __restrict__ wrecip,
    unsigned int* __restrict__ entries, int* __restrict__ counter,
    int* __restrict__ cntM)
{
    int row = blockIdx.x * 4 + (threadIdx.x >> 6);
    int lane = threadIdx.x & 63;
    const float* r = S + (long)row * NN;

    float mx = -3.402823466e38f;
    for (int m = lane; m < NN; m += 64) mx = fmaxf(mx, r[m]);
#pragma unroll
    for (int off = 32; off; off >>= 1) mx = fmaxf(mx, __shfl_xor(mx, off, 64));

    float thr = mx - 0.5f;
    bool active = fabsf(mx) > 0.5f;
    int cnt = 0;
    for (int m = lane; m < NN; m += 64) {
        if (r[m] >= thr) {
            cnt++;
            if (active) {
                unsigned pos = (unsigned)atomicAdd(counter, 1);
                if (pos < ENTRY_CAP) {
                    entries[pos] = ((unsigned)row << 11) | (unsigned)m;
                    atomicAdd(&cntM[m], 1);
                }
            }
        }
    }
#pragma unroll
    for (int off = 32; off; off >>= 1) cnt += __shfl_xor(cnt, off, 64);

    if (lane == 0)
        wrecip[row] = active ? 1.0f / fmaxf((float)cnt, 1.0f) : 0.0f;
}

// ---------------------------------------------------------------------------
// scan: single block. Exclusive prefix sum of cntM[2048] -> colOff[2049],
// and initializes cursor[m] = colOff[m].
// ---------------------------------------------------------------------------
__global__ __launch_bounds__(256) void scan_k(
    const int* __restrict__ cntM, int* __restrict__ colOff,
    int* __restrict__ cursor)
{
    __shared__ int part[256];
    int t = threadIdx.x;
    int v[8], e[8];
    int s = 0;
#pragma unroll
    for (int i = 0; i < 8; i++) {
        v[i] = cntM[t * 8 + i];
        e[i] = s;
        s += v[i];
    }
    part[t] = s;
    __syncthreads();
    // Hillis-Steele inclusive scan over 256 partials
    for (int off = 1; off < 256; off <<= 1) {
        int x = (t >= off) ? part[t - off] : 0;
        __syncthreads();
        part[t] += x;
        __syncthreads();
    }
    int base = (t > 0) ? part[t - 1] : 0;
#pragma unroll
    for (int i = 0; i < 8; i++) {
        int o = base + e[i];
        colOff[t * 8 + i] = o;
        cursor[t * 8 + i] = o;
    }
    if (t == 255) colOff[2048] = part[255];
}

// ---------------------------------------------------------------------------
// scatter: grid-stride over flat entries; place row into its column segment.
// ---------------------------------------------------------------------------
__global__ __launch_bounds__(256) void scatter_k(
    const unsigned int* __restrict__ entries, const int* __restrict__ counter,
    int* __restrict__ cursor, unsigned int* __restrict__ csrRow)
{
    int cnt = *counter;
    if (cnt > ENTRY_CAP) cnt = ENTRY_CAP;
    int idx = blockIdx.x * 256 + threadIdx.x;
    int stride = gridDim.x * 256;
    for (int ei = idx; ei < cnt; ei += stride) {
        unsigned v = entries[ei];
        int m   = v & 2047;
        int row = v >> 11;
        int slot = atomicAdd(&cursor[m], 1);
        csrRow[slot] = (unsigned)row;
    }
}

// ---------------------------------------------------------------------------
// apply: one block per output column m (exact, unbounded per-column count).
//   attnT[m][:] = X[m][:] + sum_{e in seg(m)} wrecip[row_e] * Yt[row_e][:]
// ---------------------------------------------------------------------------
__global__ __launch_bounds__(256) void apply_k(
    const unsigned int* __restrict__ csrRow, const int* __restrict__ colOff,
    const float* __restrict__ wrecip, const float* __restrict__ Yt,
    const float* __restrict__ X, float* __restrict__ attnT)
{
    int m = blockIdx.x;
    int tid = threadIdx.x;
    int beg = colOff[m], end = colOff[m + 1];

    float a0 = X[(long)m * DD + tid];
    float a1 = X[(long)m * DD + tid + 256];

    for (int e = beg; e < end; e++) {
        int row = (int)csrRow[e];
        float w = wrecip[row];
        const float* y = Yt + (long)row * DD;
        a0 += w * y[tid];
        a1 += w * y[tid + 256];
    }
    attnT[(long)m * DD + tid]       = a0;
    attnT[(long)m * DD + tid + 256] = a1;
}

// ---------------------------------------------------------------------------
// transpose: src [R,C] -> dst [C,R]. 32x32 LDS tiles, 256 threads.
// ---------------------------------------------------------------------------
__global__ __launch_bounds__(256) void transpose_k(
    const float* __restrict__ src, float* __restrict__ dst, int R, int C)
{
    __shared__ float t[32][33];
    int tx = threadIdx.x & 31, ty = threadIdx.x >> 5;
    int c0 = blockIdx.x * 32, r0 = blockIdx.y * 32;
#pragma unroll
    for (int k = 0; k < 4; k++)
        t[ty + 8 * k][tx] = src[(long)(r0 + ty + 8 * k) * C + c0 + tx];
    __syncthreads();
#pragma unroll
    for (int k = 0; k < 4; k++)
        dst[(long)(c0 + ty + 8 * k) * R + r0 + tx] = t[tx][ty + 8 * k];
}

// ---------------------------------------------------------------------------
// Workspace layout (floats / 4-byte words):
//   region0 : 16777216 (64MB)  S [H,N,N]; Yt [H,N,D] & ff1T [N,DFF] alias it
//   KX      :   524288         [H*Q, N]
//   wrecip  :     8192
//   attnT   :  1048576         [N, D]
//   XbufA   :  1048576         [N, D]
//   XbufB   :  1048576
//   entries :   262144 (uint)
//   csrRow  :   262144 (uint)
//   colOff  :     2112 (int)   [2049 used]
//   cursor  :     2048 (int)
//   cntM    :     2048 (int)
//   counters:       64 (int)
// total ~84 MB (R1 proved ws_size >= 94.4 MB)
// ---------------------------------------------------------------------------
extern "C" void kernel_launch(void* const* d_in, const int* in_sizes, int n_in,
                              void* d_out, int out_size, void* d_ws, size_t ws_size,
                              hipStream_t stream)
{
    const float* X0 = (const float*)d_in[0];
    const float* Kw = (const float*)d_in[1];
    const float* Vw = (const float*)d_in[2];
    const float* W1 = (const float*)d_in[3];
    const float* b1 = (const float*)d_in[4];
    const float* W2 = (const float*)d_in[5];
    const float* b2 = (const float*)d_in[6];
    float* out = (float*)d_out;

    float* ws      = (float*)d_ws;
    float* S       = ws;                         // 16777216
    float* Yt      = ws;                         // alias (after extract)
    float* ff1T    = ws;                         // alias (after apply)
    float* KX      = ws + 16777216;              // 524288
    float* wrecip  = KX + 524288;                // 8192
    float* attnT   = wrecip + 8192;              // 1048576
    float* XbufA   = attnT + 1048576;            // 1048576
    float* XbufB   = XbufA + 1048576;            // 1048576
    unsigned int* entries = (unsigned int*)(XbufB + 1048576);  // 262144
    unsigned int* csrRow  = entries + ENTRY_CAP;               // 262144
    int* colOff    = (int*)(csrRow + ENTRY_CAP);               // 2112
    int* cursor    = colOff + 2112;                            // 2048
    int* cntM      = cursor + 2048;                            // 2048
    int* counters  = cntM + 2048;                              // 64

    // XT0 = X0^T  [N, D]
    transpose_k<<<dim3(NN / 32, DD / 32), 256, 0, stream>>>(X0, XbufA, DD, NN);

    float* Xc = XbufA;
    for (int li = 0; li < LL; li++) {
        float* Xn = (li & 1) ? XbufA : XbufB;

        // 1) KX = K_l @ XT^T   [H*Q, N]
        gemm_k<0, 1, 0><<<dim3(NN / 64, (HH * QQ) / 64, 1), 256, 0, stream>>>(
            Kw + (long)li * HH * QQ * DD, Xc, KX, nullptr, nullptr,
            HH * QQ, NN, DD, DD, DD, NN, 0, 0, 0);

        // 2) S_h = KX_h^T @ KX_h   [N, N] batch H
        gemm_k<1, 0, 0><<<dim3(NN / 64, NN / 64, HH), 256, 0, stream>>>(
            KX, KX, S, nullptr, nullptr,
            NN, NN, QQ, NN, NN, NN,
            (long)QQ * NN, (long)QQ * NN, (long)NN * NN);

        // 3) mask extraction -> flat entries + per-column counts -> CSR
        zero_k<<<dim3(NN / 256), 256, 0, stream>>>(cntM, counters + li);
        extract_k<<<dim3(HH * NN / 4), 256, 0, stream>>>(
            S, wrecip, entries, counters + li, cntM);
        scan_k<<<dim3(1), 256, 0, stream>>>(cntM, colOff, cursor);
        scatter_k<<<dim3(64), 256, 0, stream>>>(entries, counters + li, cursor, csrRow);

        // 4) Yt_h = XT @ V_h^T   [N, D] batch H (A shared; aliases dead S)
        gemm_k<0, 1, 0><<<dim3(DD / 64, NN / 64, HH), 256, 0, stream>>>(
            Xc, Vw + (long)li * HH * DD * DD, Yt, nullptr, nullptr,
            NN, DD, DD, DD, DD, DD,
            0, (long)DD * DD, (long)NN * DD);

        // 5) attnT = XT + sparse combine (CSR gather, no atomics, exact)
        apply_k<<<dim3(NN), 256, 0, stream>>>(csrRow, colOff, wrecip, Yt, Xc, attnT);

        // 6) ff1T = relu(attnT @ W1^T + b1)   [N, DFF] (aliases dead Yt)
        gemm_k<0, 1, 1><<<dim3(DFFC / 64, NN / 64, 1), 256, 0, stream>>>(
            attnT, W1 + (long)li * DFFC * DD, ff1T, b1 + (long)li * DFFC, nullptr,
            NN, DFFC, DD, DD, DD, DFFC, 0, 0, 0);

        // 7) XT' = ff1T @ W2^T + b2 + attnT   [N, D]
        gemm_k<0, 1, 0><<<dim3(DD / 64, NN / 64, 1), 256, 0, stream>>>(
            ff1T, W2 + (long)li * DD * DFFC, Xn, b2 + (long)li * DD, attnT,
            NN, DD, DFFC, DFFC, DFFC, DD, 0, 0, 0);

        Xc = Xn;
    }

    // out = XT_final^T  [D, N]
    transpose_k<<<dim3(DD / 32, NN / 32), 256, 0, stream>>>(Xc, out, NN, DD);
}

// Round 5
// 4172.832 us; speedup vs baseline: 2.7926x; 2.7926x over previous
//
#include <hip/hip_runtime.h>

// Problem constants
#define LL   8
#define HH   4
#define QQ   64
#define DD   512
#define NN   2048
#define DFFC 2048
#define ENTRY_CAP (1 << 18)
#define CHUNK 8
#define APPLY_BLOCKS 2048

// ---------------------------------------------------------------------------
// Generic fp32 tiled GEMM: C = op(A) @ op(B) (+bias per COLUMN)(+relu)(+res)
//   (unchanged from R2/R4-passing code)
// ---------------------------------------------------------------------------
template <int TRANSA, int TRANSB, int RELU>
__global__ __launch_bounds__(256) void gemm_k(
    const float* __restrict__ A, const float* __restrict__ B,
    float* __restrict__ C, const float* __restrict__ bias,
    const float* __restrict__ res, int M, int N, int K,
    int lda, int ldb, int ldc, long sA, long sB, long sC)
{
    int bz = blockIdx.z;
    A += bz * sA;
    B += bz * sB;
    C += bz * sC;

    __shared__ float As[16][68];
    __shared__ float Bs[16][68];

    const int tid = threadIdx.x;
    const int tx = tid & 15;
    const int ty = tid >> 4;
    const int rowBase = blockIdx.y * 64;
    const int colBase = blockIdx.x * 64;

    float acc[4][4] = {};

    for (int k0 = 0; k0 < K; k0 += 16) {
        if (TRANSA) {
            int m = tid & 63, kk = tid >> 6;
#pragma unroll
            for (int p = 0; p < 4; p++)
                As[kk + 4 * p][m] = A[(long)(k0 + kk + 4 * p) * lda + rowBase + m];
        } else {
            int kk = tid & 15, mm = tid >> 4;
#pragma unroll
            for (int p = 0; p < 4; p++)
                As[kk][mm + 16 * p] = A[(long)(rowBase + mm + 16 * p) * lda + k0 + kk];
        }
        if (TRANSB) {
            int kk = tid & 15, nn = tid >> 4;
#pragma unroll
            for (int p = 0; p < 4; p++)
                Bs[kk][nn + 16 * p] = B[(long)(colBase + nn + 16 * p) * ldb + k0 + kk];
        } else {
            int n = tid & 63, kk = tid >> 6;
#pragma unroll
            for (int p = 0; p < 4; p++)
                Bs[kk + 4 * p][n] = B[(long)(k0 + kk + 4 * p) * ldb + colBase + n];
        }
        __syncthreads();

#pragma unroll
        for (int kk = 0; kk < 16; kk++) {
            float a0 = As[kk][ty * 4 + 0];
            float a1 = As[kk][ty * 4 + 1];
            float a2 = As[kk][ty * 4 + 2];
            float a3 = As[kk][ty * 4 + 3];
            float b0 = Bs[kk][tx * 4 + 0];
            float b1 = Bs[kk][tx * 4 + 1];
            float b2 = Bs[kk][tx * 4 + 2];
            float b3 = Bs[kk][tx * 4 + 3];
            acc[0][0] += a0 * b0; acc[0][1] += a0 * b1; acc[0][2] += a0 * b2; acc[0][3] += a0 * b3;
            acc[1][0] += a1 * b0; acc[1][1] += a1 * b1; acc[1][2] += a1 * b2; acc[1][3] += a1 * b3;
            acc[2][0] += a2 * b0; acc[2][1] += a2 * b1; acc[2][2] += a2 * b2; acc[2][3] += a2 * b3;
            acc[3][0] += a3 * b0; acc[3][1] += a3 * b1; acc[3][2] += a3 * b2; acc[3][3] += a3 * b3;
        }
        __syncthreads();
    }

#pragma unroll
    for (int i = 0; i < 4; i++) {
        int r = rowBase + ty * 4 + i;
#pragma unroll
        for (int j = 0; j < 4; j++) {
            int c = colBase + tx * 4 + j;
            float v = acc[i][j];
            if (bias) v += bias[c];
            if (RELU) v = fmaxf(v, 0.0f);
            if (res) v += res[(long)r * ldc + c];
            C[(long)r * ldc + c] = v;
        }
    }
}

// ---------------------------------------------------------------------------
// zero: one-time reset of cntM[2048] and all LL per-layer flat counters.
// ---------------------------------------------------------------------------
__global__ __launch_bounds__(256) void zero_k(int* __restrict__ cntM,
                                              int* __restrict__ counters)
{
    int i = blockIdx.x * 256 + threadIdx.x;
    cntM[i] = 0;
    if (i < LL) counters[i] = 0;
}

// ---------------------------------------------------------------------------
// extract: one wave per score row (h,n). Computes wrecip and emits flat
// packed entries (row<<11 | m) + per-column counts cntM[m].
// ---------------------------------------------------------------------------
__global__ __launch_bounds__(256) void extract_k(
    const float* __restrict__ S, float* __restrict__ wrecip,
    unsigned int* __restrict__ entries, int* __restrict__ counter,
    int* __restrict__ cntM)
{
    int row = blockIdx.x * 4 + (threadIdx.x >> 6);
    int lane = threadIdx.x & 63;
    const float* r = S + (long)row * NN;

    float mx = -3.402823466e38f;
    for (int m = lane; m < NN; m += 64) mx = fmaxf(mx, r[m]);
#pragma unroll
    for (int off = 32; off; off >>= 1) mx = fmaxf(mx, __shfl_xor(mx, off, 64));

    float thr = mx - 0.5f;
    bool active = fabsf(mx) > 0.5f;
    int cnt = 0;
    for (int m = lane; m < NN; m += 64) {
        if (r[m] >= thr) {
            cnt++;
            if (active) {
                unsigned pos = (unsigned)atomicAdd(counter, 1);
                if (pos < ENTRY_CAP) {
                    entries[pos] = ((unsigned)row << 11) | (unsigned)m;
                    atomicAdd(&cntM[m], 1);
                }
            }
        }
    }
#pragma unroll
    for (int off = 32; off; off >>= 1) cnt += __shfl_xor(cnt, off, 64);

    if (lane == 0)
        wrecip[row] = active ? 1.0f / fmaxf((float)cnt, 1.0f) : 0.0f;
}

// ---------------------------------------------------------------------------
// scan: single block. Exclusive prefix sum cntM[2048] -> colOff[2049],
// cursor init, and RE-ZEROES cntM for the next layer.
// ---------------------------------------------------------------------------
__global__ __launch_bounds__(256) void scan_k(
    int* __restrict__ cntM, int* __restrict__ colOff, int* __restrict__ cursor)
{
    __shared__ int part[256];
    int t = threadIdx.x;
    int e[8];
    int s = 0;
#pragma unroll
    for (int i = 0; i < 8; i++) {
        int v = cntM[t * 8 + i];
        cntM[t * 8 + i] = 0;
        e[i] = s;
        s += v;
    }
    part[t] = s;
    __syncthreads();
    for (int off = 1; off < 256; off <<= 1) {
        int x = (t >= off) ? part[t - off] : 0;
        __syncthreads();
        part[t] += x;
        __syncthreads();
    }
    int base = (t > 0) ? part[t - 1] : 0;
#pragma unroll
    for (int i = 0; i < 8; i++) {
        int o = base + e[i];
        colOff[t * 8 + i] = o;
        cursor[t * 8 + i] = o;
    }
    if (t == 255) colOff[2048] = part[255];
}

// ---------------------------------------------------------------------------
// scatter: grid-stride over flat entries; place full packed entry into its
// column-sorted position (CSR order).
// ---------------------------------------------------------------------------
__global__ __launch_bounds__(256) void scatter_k(
    const unsigned int* __restrict__ entries, const int* __restrict__ counter,
    int* __restrict__ cursor, unsigned int* __restrict__ csr)
{
    int cnt = *counter;
    if (cnt > ENTRY_CAP) cnt = ENTRY_CAP;
    int idx = blockIdx.x * 256 + threadIdx.x;
    int stride = gridDim.x * 256;
    for (int ei = idx; ei < cnt; ei += stride) {
        unsigned v = entries[ei];
        int m = v & 2047;
        int slot = atomicAdd(&cursor[m], 1);
        csr[slot] = v;
    }
}

// ---------------------------------------------------------------------------
// initattn: attnT = X  (residual base), [N, D] float4 copy.
// ---------------------------------------------------------------------------
__global__ __launch_bounds__(256) void initattn_k(
    const float* __restrict__ X, float* __restrict__ attnT)
{
    long i = (long)blockIdx.x * 256 + threadIdx.x;
    ((float4*)attnT)[i] = ((const float4*)X)[i];
}

// ---------------------------------------------------------------------------
// apply: entry-parallel over column-sorted CSR entries, CHUNK per block
// (grid-stride). Register-accumulate per column-run, one atomicAdd set per
// run. Load-balanced across hub columns.
// ---------------------------------------------------------------------------
__global__ __launch_bounds__(256) void apply_k(
    const unsigned int* __restrict__ csr, const int* __restrict__ colOff,
    const float* __restrict__ wrecip, const float* __restrict__ Yt,
    float* __restrict__ attnT)
{
    const int total = colOff[NN];
    const int tid = threadIdx.x;

    for (int base = blockIdx.x * CHUNK; base < total;
         base += gridDim.x * CHUNK) {
        int end = base + CHUNK;
        if (end > total) end = total;

        float a0 = 0.0f, a1 = 0.0f;
        int curM = -1;
        for (int e = base; e < end; e++) {
            unsigned v = csr[e];
            int m = v & 2047;
            int row = (int)(v >> 11);
            if (m != curM) {                       // wave-uniform branch
                if (curM >= 0) {
                    atomicAdd(&attnT[(long)curM * DD + tid], a0);
                    atomicAdd(&attnT[(long)curM * DD + tid + 256], a1);
                }
                curM = m;
                a0 = a1 = 0.0f;
            }
            float w = wrecip[row];
            const float* y = Yt + (long)row * DD;
            a0 += w * y[tid];
            a1 += w * y[tid + 256];
        }
        if (curM >= 0) {
            atomicAdd(&attnT[(long)curM * DD + tid], a0);
            atomicAdd(&attnT[(long)curM * DD + tid + 256], a1);
        }
    }
}

// ---------------------------------------------------------------------------
// transpose: src [R,C] -> dst [C,R]. 32x32 LDS tiles, 256 threads.
// ---------------------------------------------------------------------------
__global__ __launch_bounds__(256) void transpose_k(
    const float* __restrict__ src, float* __restrict__ dst, int R, int C)
{
    __shared__ float t[32][33];
    int tx = threadIdx.x & 31, ty = threadIdx.x >> 5;
    int c0 = blockIdx.x * 32, r0 = blockIdx.y * 32;
#pragma unroll
    for (int k = 0; k < 4; k++)
        t[ty + 8 * k][tx] = src[(long)(r0 + ty + 8 * k) * C + c0 + tx];
    __syncthreads();
#pragma unroll
    for (int k = 0; k < 4; k++)
        dst[(long)(c0 + ty + 8 * k) * R + r0 + tx] = t[tx][ty + 8 * k];
}

// ---------------------------------------------------------------------------
// Workspace layout (4-byte words): ~84 MB total (R1 proved ws >= 94.4 MB)
// ---------------------------------------------------------------------------
extern "C" void kernel_launch(void* const* d_in, const int* in_sizes, int n_in,
                              void* d_out, int out_size, void* d_ws, size_t ws_size,
                              hipStream_t stream)
{
    const float* X0 = (const float*)d_in[0];
    const float* Kw = (const float*)d_in[1];
    const float* Vw = (const float*)d_in[2];
    const float* W1 = (const float*)d_in[3];
    const float* b1 = (const float*)d_in[4];
    const float* W2 = (const float*)d_in[5];
    const float* b2 = (const float*)d_in[6];
    float* out = (float*)d_out;

    float* ws      = (float*)d_ws;
    float* S       = ws;                         // 16777216
    float* Yt      = ws;                         // alias (after extract)
    float* ff1T    = ws;                         // alias (after apply)
    float* KX      = ws + 16777216;              // 524288
    float* wrecip  = KX + 524288;                // 8192
    float* attnT   = wrecip + 8192;              // 1048576
    float* XbufA   = attnT + 1048576;            // 1048576
    float* XbufB   = XbufA + 1048576;            // 1048576
    unsigned int* entries = (unsigned int*)(XbufB + 1048576);  // 262144
    unsigned int* csr     = entries + ENTRY_CAP;               // 262144
    int* colOff    = (int*)(csr + ENTRY_CAP);                  // 2112
    int* cursor    = colOff + 2112;                            // 2048
    int* cntM      = cursor + 2048;                            // 2048
    int* counters  = cntM + 2048;                              // 64

    zero_k<<<dim3(NN / 256), 256, 0, stream>>>(cntM, counters);

    // XT0 = X0^T  [N, D]
    transpose_k<<<dim3(NN / 32, DD / 32), 256, 0, stream>>>(X0, XbufA, DD, NN);

    float* Xc = XbufA;
    for (int li = 0; li < LL; li++) {
        float* Xn = (li & 1) ? XbufA : XbufB;

        // 1) KX = K_l @ XT^T   [H*Q, N]
        gemm_k<0, 1, 0><<<dim3(NN / 64, (HH * QQ) / 64, 1), 256, 0, stream>>>(
            Kw + (long)li * HH * QQ * DD, Xc, KX, nullptr, nullptr,
            HH * QQ, NN, DD, DD, DD, NN, 0, 0, 0);

        // 2) S_h = KX_h^T @ KX_h   [N, N] batch H
        gemm_k<1, 0, 0><<<dim3(NN / 64, NN / 64, HH), 256, 0, stream>>>(
            KX, KX, S, nullptr, nullptr,
            NN, NN, QQ, NN, NN, NN,
            (long)QQ * NN, (long)QQ * NN, (long)NN * NN);

        // 3) mask extraction -> CSR (scan re-zeroes cntM for next layer)
        extract_k<<<dim3(HH * NN / 4), 256, 0, stream>>>(
            S, wrecip, entries, counters + li, cntM);
        scan_k<<<dim3(1), 256, 0, stream>>>(cntM, colOff, cursor);
        scatter_k<<<dim3(64), 256, 0, stream>>>(entries, counters + li, cursor, csr);

        // 4) Yt_h = XT @ V_h^T   [N, D] batch H (A shared; aliases dead S)
        gemm_k<0, 1, 0><<<dim3(DD / 64, NN / 64, HH), 256, 0, stream>>>(
            Xc, Vw + (long)li * HH * DD * DD, Yt, nullptr, nullptr,
            NN, DD, DD, DD, DD, DD,
            0, (long)DD * DD, (long)NN * DD);

        // 5) attnT = XT; attnT += sparse combine (entry-parallel, balanced)
        initattn_k<<<dim3(NN * DD / 4 / 256), 256, 0, stream>>>(Xc, attnT);
        apply_k<<<dim3(APPLY_BLOCKS), 256, 0, stream>>>(csr, colOff, wrecip, Yt, attnT);

        // 6) ff1T = relu(attnT @ W1^T + b1)   [N, DFF] (aliases dead Yt)
        gemm_k<0, 1, 1><<<dim3(DFFC / 64, NN / 64, 1), 256, 0, stream>>>(
            attnT, W1 + (long)li * DFFC * DD, ff1T, b1 + (long)li * DFFC, nullptr,
            NN, DFFC, DD, DD, DD, DFFC, 0, 0, 0);

        // 7) XT' = ff1T @ W2^T + b2 + attnT   [N, D]
        gemm_k<0, 1, 0><<<dim3(DD / 64, NN / 64, 1), 256, 0, stream>>>(
            ff1T, W2 + (long)li * DD * DFFC, Xn, b2 + (long)li * DD, attnT,
            NN, DD, DFFC, DFFC, DFFC, DD, 0, 0, 0);

        Xc = Xn;
    }

    // out = XT_final^T  [D, N]
    transpose_k<<<dim3(DD / 32, NN / 32), 256, 0, stream>>>(Xc, out, NN, DD);
}

// Round 6
// 3454.277 us; speedup vs baseline: 3.3735x; 1.2080x over previous
//
#include <hip/hip_runtime.h>

// Problem constants
#define LL   8
#define HH   4
#define QQ   64
#define DD   512
#define NN   2048
#define DFFC 2048
#define ENTRY_CAP (1 << 17)
#define CHUNK 8
#define APPLY_BLOCKS 2048

typedef short     bf16x8 __attribute__((ext_vector_type(8)));  // 8 bf16 = 4 VGPR
typedef float     f32x4  __attribute__((ext_vector_type(4)));  // MFMA C/D frag
typedef unsigned short u16;

// fp32 -> (hi, lo) bf16 split, RNE. x ~= hi + lo with ~16-bit mantissa coverage.
__device__ inline void splitf(float v, u16& h, u16& l)
{
    unsigned u  = __float_as_uint(v);
    unsigned uh = u + (0x7FFFu + ((u >> 16) & 1u));
    h = (u16)(uh >> 16);
    float fh = __uint_as_float(((unsigned)h) << 16);
    float r  = v - fh;
    unsigned ur = __float_as_uint(r);
    unsigned ul = ur + (0x7FFFu + ((ur >> 16) & 1u));
    l = (u16)(ul >> 16);
}

// ---------------------------------------------------------------------------
// Split-bf16 MFMA GEMM (NT): C[M,N] = A[M,K] @ B[N,K]^T computed as
//   hi*hi + hi*lo + lo*hi  (fp32 accumulate; rel err ~2^-17).
// Block 256 thr = 4 waves (2x2), block tile 128x128, wave tile 64x64 =
// 4x4 mfma_f32_16x16x32_bf16 frags. Direct global->VGPR fragment loads
// (both operands k-contiguous; 16B/lane dwordx4).
// A-frag: lane reads A[mBase+i*16+(l&15)][k0+(l>>4)*8 ..+8]; B symmetric.
// C/D: n = nBase+j*16+(l&15), m = mBase+i*16+(l>>4)*4+reg  (verified layout).
// Epilogue: optional bias(col n) / relu / fp32 write / bf16 hi-lo split write.
// Batched via blockIdx.z: element offsets sAoff/sBoff/sCoff.
// ---------------------------------------------------------------------------
template <int BIAS, int RELU, int WF32, int WSPLIT>
__global__ __launch_bounds__(256) void mgemm_k(
    const u16* __restrict__ Ahi, const u16* __restrict__ Alo,
    const u16* __restrict__ Bhi, const u16* __restrict__ Blo,
    float* __restrict__ C, u16* __restrict__ Chi, u16* __restrict__ Clo,
    const float* __restrict__ bias,
    int M, int N, int K, int lda, int ldb, int ldc,
    long sAoff, long sBoff, long sCoff)
{
    const int bz = blockIdx.z;
    Ahi += bz * sAoff;  Alo += bz * sAoff;
    Bhi += bz * sBoff;  Blo += bz * sBoff;
    const long cOff = (long)bz * sCoff;

    const int tid  = threadIdx.x;
    const int wave = tid >> 6, lane = tid & 63;
    const int quad = lane >> 4, l15 = lane & 15;
    const int wy = wave >> 1, wx = wave & 1;
    const int mBase = blockIdx.y * 128 + wy * 64;
    const int nBase = blockIdx.x * 128 + wx * 64;

    f32x4 acc[4][4];
#pragma unroll
    for (int i = 0; i < 4; i++)
#pragma unroll
        for (int j = 0; j < 4; j++)
            acc[i][j] = (f32x4){0.f, 0.f, 0.f, 0.f};

    for (int k0 = 0; k0 < K; k0 += 32) {
        const int kk = k0 + quad * 8;
        bf16x8 ah[4], al[4], bh[4], bl[4];
#pragma unroll
        for (int i = 0; i < 4; i++) {
            long ar = (long)(mBase + i * 16 + l15) * lda + kk;
            ah[i] = *(const bf16x8*)(Ahi + ar);
            al[i] = *(const bf16x8*)(Alo + ar);
            long br = (long)(nBase + i * 16 + l15) * ldb + kk;
            bh[i] = *(const bf16x8*)(Bhi + br);
            bl[i] = *(const bf16x8*)(Blo + br);
        }
#pragma unroll
        for (int i = 0; i < 4; i++)
#pragma unroll
            for (int j = 0; j < 4; j++) {
                acc[i][j] = __builtin_amdgcn_mfma_f32_16x16x32_bf16(ah[i], bh[j], acc[i][j], 0, 0, 0);
                acc[i][j] = __builtin_amdgcn_mfma_f32_16x16x32_bf16(ah[i], bl[j], acc[i][j], 0, 0, 0);
                acc[i][j] = __builtin_amdgcn_mfma_f32_16x16x32_bf16(al[i], bh[j], acc[i][j], 0, 0, 0);
            }
    }

#pragma unroll
    for (int i = 0; i < 4; i++) {
#pragma unroll
        for (int j = 0; j < 4; j++) {
            const int n = nBase + j * 16 + l15;
            const float bv = BIAS ? bias[n] : 0.0f;
#pragma unroll
            for (int r = 0; r < 4; r++) {
                const int m = mBase + i * 16 + quad * 4 + r;
                float v = acc[i][j][r] + bv;
                if (RELU) v = fmaxf(v, 0.0f);
                const long o = cOff + (long)m * ldc + n;
                if (WF32) C[o] = v;
                if (WSPLIT) {
                    u16 h, l;
                    splitf(v, h, l);
                    Chi[o] = h;
                    Clo[o] = l;
                }
            }
        }
    }
}

// ---------------------------------------------------------------------------
// split: fp32 array -> hi/lo bf16 arrays (float4 / ushort4 vectorized).
// ---------------------------------------------------------------------------
__global__ __launch_bounds__(256) void split_k(
    const float* __restrict__ src, u16* __restrict__ hi, u16* __restrict__ lo)
{
    int i = blockIdx.x * 256 + threadIdx.x;
    float4 v = ((const float4*)src)[i];
    ushort4 hv, lv;
    splitf(v.x, hv.x, lv.x);
    splitf(v.y, hv.y, lv.y);
    splitf(v.z, hv.z, lv.z);
    splitf(v.w, hv.w, lv.w);
    ((ushort4*)hi)[i] = hv;
    ((ushort4*)lo)[i] = lv;
}

// ---------------------------------------------------------------------------
// splitw: per-layer weight split (K | V | W1 | W2) in one launch.
// vec4 ranges: K 32768 | V 262144 | W1 262144 | W2 262144  (total 819200)
// ---------------------------------------------------------------------------
__global__ __launch_bounds__(256) void splitw_k(
    const float* __restrict__ K_, const float* __restrict__ V_,
    const float* __restrict__ W1_, const float* __restrict__ W2_,
    u16* __restrict__ Khi, u16* __restrict__ Klo,
    u16* __restrict__ Vhi, u16* __restrict__ Vlo,
    u16* __restrict__ W1hi, u16* __restrict__ W1lo,
    u16* __restrict__ W2hi, u16* __restrict__ W2lo)
{
    int i = blockIdx.x * 256 + threadIdx.x;
    const float* s;
    u16 *h, *l;
    int off;
    if (i < 32768)       { s = K_;  h = Khi;  l = Klo;  off = i; }
    else if (i < 294912) { s = V_;  h = Vhi;  l = Vlo;  off = i - 32768; }
    else if (i < 557056) { s = W1_; h = W1hi; l = W1lo; off = i - 294912; }
    else                 { s = W2_; h = W2hi; l = W2lo; off = i - 557056; }
    float4 v = ((const float4*)s)[off];
    ushort4 hv, lv;
    splitf(v.x, hv.x, lv.x);
    splitf(v.y, hv.y, lv.y);
    splitf(v.z, hv.z, lv.z);
    splitf(v.w, hv.w, lv.w);
    ((ushort4*)h)[off] = hv;
    ((ushort4*)l)[off] = lv;
}

// ---------------------------------------------------------------------------
// zero: one-time reset of cntM[2048] and all LL per-layer flat counters.
// ---------------------------------------------------------------------------
__global__ __launch_bounds__(256) void zero_k(int* __restrict__ cntM,
                                              int* __restrict__ counters)
{
    int i = blockIdx.x * 256 + threadIdx.x;
    cntM[i] = 0;
    if (i < LL) counters[i] = 0;
}

// ---------------------------------------------------------------------------
// extract: one wave per score row n of per-head Sh [NN,NN]. Global row id =
// rowOff + n. Emits wrecip + flat packed entries (row<<11|m) + cntM[m].
// ---------------------------------------------------------------------------
__global__ __launch_bounds__(256) void extract_k(
    const float* __restrict__ Sh, float* __restrict__ wrecip,
    unsigned int* __restrict__ entries, int* __restrict__ counter,
    int* __restrict__ cntM, int rowOff)
{
    int n = blockIdx.x * 4 + (threadIdx.x >> 6);
    int lane = threadIdx.x & 63;
    const float* r = Sh + (long)n * NN;
    const int row = rowOff + n;

    float mx = -3.402823466e38f;
    for (int m = lane; m < NN; m += 64) mx = fmaxf(mx, r[m]);
#pragma unroll
    for (int off = 32; off; off >>= 1) mx = fmaxf(mx, __shfl_xor(mx, off, 64));

    float thr = mx - 0.5f;
    bool active = fabsf(mx) > 0.5f;
    int cnt = 0;
    for (int m = lane; m < NN; m += 64) {
        if (r[m] >= thr) {
            cnt++;
            if (active) {
                unsigned pos = (unsigned)atomicAdd(counter, 1);
                if (pos < ENTRY_CAP) {
                    entries[pos] = ((unsigned)row << 11) | (unsigned)m;
                    atomicAdd(&cntM[m], 1);
                }
            }
        }
    }
#pragma unroll
    for (int off = 32; off; off >>= 1) cnt += __shfl_xor(cnt, off, 64);

    if (lane == 0)
        wrecip[row] = active ? 1.0f / fmaxf((float)cnt, 1.0f) : 0.0f;
}

// ---------------------------------------------------------------------------
// scan: single block. Exclusive prefix sum cntM[2048] -> colOff[2049],
// cursor init, re-zero cntM for next layer.
// ---------------------------------------------------------------------------
__global__ __launch_bounds__(256) void scan_k(
    int* __restrict__ cntM, int* __restrict__ colOff, int* __restrict__ cursor)
{
    __shared__ int part[256];
    int t = threadIdx.x;
    int e[8];
    int s = 0;
#pragma unroll
    for (int i = 0; i < 8; i++) {
        int v = cntM[t * 8 + i];
        cntM[t * 8 + i] = 0;
        e[i] = s;
        s += v;
    }
    part[t] = s;
    __syncthreads();
    for (int off = 1; off < 256; off <<= 1) {
        int x = (t >= off) ? part[t - off] : 0;
        __syncthreads();
        part[t] += x;
        __syncthreads();
    }
    int base = (t > 0) ? part[t - 1] : 0;
#pragma unroll
    for (int i = 0; i < 8; i++) {
        int o = base + e[i];
        colOff[t * 8 + i] = o;
        cursor[t * 8 + i] = o;
    }
    if (t == 255) colOff[2048] = part[255];
}

// ---------------------------------------------------------------------------
// scatter: flat entries -> column-sorted CSR order.
// ---------------------------------------------------------------------------
__global__ __launch_bounds__(256) void scatter_k(
    const unsigned int* __restrict__ entries, const int* __restrict__ counter,
    int* __restrict__ cursor, unsigned int* __restrict__ csr)
{
    int cnt = *counter;
    if (cnt > ENTRY_CAP) cnt = ENTRY_CAP;
    int idx = blockIdx.x * 256 + threadIdx.x;
    int stride = gridDim.x * 256;
    for (int ei = idx; ei < cnt; ei += stride) {
        unsigned v = entries[ei];
        int m = v & 2047;
        int slot = atomicAdd(&cursor[m], 1);
        csr[slot] = v;
    }
}

// ---------------------------------------------------------------------------
// initattn: attnT = X (residual base), float4 copy.
// ---------------------------------------------------------------------------
__global__ __launch_bounds__(256) void initattn_k(
    const float* __restrict__ X, float* __restrict__ attnT)
{
    long i = (long)blockIdx.x * 256 + threadIdx.x;
    ((float4*)attnT)[i] = ((const float4*)X)[i];
}

// ---------------------------------------------------------------------------
// apply: entry-parallel over column-sorted CSR, CHUNK entries per block,
// register-accumulate per column-run, one atomicAdd set per run. (R5-proven)
// ---------------------------------------------------------------------------
__global__ __launch_bounds__(256) void apply_k(
    const unsigned int* __restrict__ csr, const int* __restrict__ colOff,
    const float* __restrict__ wrecip, const float* __restrict__ Yt,
    float* __restrict__ attnT)
{
    const int total = colOff[NN];
    const int tid = threadIdx.x;

    for (int base = blockIdx.x * CHUNK; base < total;
         base += gridDim.x * CHUNK) {
        int end = base + CHUNK;
        if (end > total) end = total;

        float a0 = 0.0f, a1 = 0.0f;
        int curM = -1;
        for (int e = base; e < end; e++) {
            unsigned v = csr[e];
            int m = v & 2047;
            int row = (int)(v >> 11);
            if (m != curM) {
                if (curM >= 0) {
                    atomicAdd(&attnT[(long)curM * DD + tid], a0);
                    atomicAdd(&attnT[(long)curM * DD + tid + 256], a1);
                }
                curM = m;
                a0 = a1 = 0.0f;
            }
            float w = wrecip[row];
            const float* y = Yt + (long)row * DD;
            a0 += w * y[tid];
            a1 += w * y[tid + 256];
        }
        if (curM >= 0) {
            atomicAdd(&attnT[(long)curM * DD + tid], a0);
            atomicAdd(&attnT[(long)curM * DD + tid + 256], a1);
        }
    }
}

// ---------------------------------------------------------------------------
// ff2red: Xn = sum_{s<4} Cpart[s] + b2(col) + attnT; write fp32 + hi/lo.
// float4 over [NN, DD]; row length 512 = 128 vec4.
// ---------------------------------------------------------------------------
__global__ __launch_bounds__(256) void ff2red_k(
    const float* __restrict__ Cpart, const float* __restrict__ b2,
    const float* __restrict__ attnT, float* __restrict__ Xn,
    u16* __restrict__ Xhi, u16* __restrict__ Xlo)
{
    int i = blockIdx.x * 256 + threadIdx.x;      // vec4 index
    float4 v0 = ((const float4*)(Cpart))[i];
    float4 v1 = ((const float4*)(Cpart + 1048576))[i];
    float4 v2 = ((const float4*)(Cpart + 2097152))[i];
    float4 v3 = ((const float4*)(Cpart + 3145728))[i];
    float4 bv = ((const float4*)b2)[i & 127];
    float4 rv = ((const float4*)attnT)[i];
    float4 o;
    o.x = v0.x + v1.x + v2.x + v3.x + bv.x + rv.x;
    o.y = v0.y + v1.y + v2.y + v3.y + bv.y + rv.y;
    o.z = v0.z + v1.z + v2.z + v3.z + bv.z + rv.z;
    o.w = v0.w + v1.w + v2.w + v3.w + bv.w + rv.w;
    ((float4*)Xn)[i] = o;
    ushort4 hv, lv;
    splitf(o.x, hv.x, lv.x);
    splitf(o.y, hv.y, lv.y);
    splitf(o.z, hv.z, lv.z);
    splitf(o.w, hv.w, lv.w);
    ((ushort4*)Xhi)[i] = hv;
    ((ushort4*)Xlo)[i] = lv;
}

// ---------------------------------------------------------------------------
// transpose: src [R,C] -> dst [C,R]. 32x32 LDS tiles.
// ---------------------------------------------------------------------------
__global__ __launch_bounds__(256) void transpose_k(
    const float* __restrict__ src, float* __restrict__ dst, int R, int C)
{
    __shared__ float t[32][33];
    int tx = threadIdx.x & 31, ty = threadIdx.x >> 5;
    int c0 = blockIdx.x * 32, r0 = blockIdx.y * 32;
#pragma unroll
    for (int k = 0; k < 4; k++)
        t[ty + 8 * k][tx] = src[(long)(r0 + ty + 8 * k) * C + c0 + tx];
    __syncthreads();
#pragma unroll
    for (int k = 0; k < 4; k++)
        dst[(long)(c0 + ty + 8 * k) * R + r0 + tx] = t[tx][ty + 8 * k];
}

// ---------------------------------------------------------------------------
// Workspace (4-byte words), total 21,903,488 words = 87.6 MB (< proven 94.4):
//  region0 (13,631,488):
//    Sh/Yt   @0         (4,194,304)   per-head scores, then Yt [H,NN,DD]
//    ff1hi   @4,194,304 (2,097,152)   bf16 [NN,DFF]
//    ff1lo   @6,291,456 (2,097,152)
//    Cpart   @8,388,608 (4,194,304)   4 split-K slabs [NN,DD]
//    attnT   @12,582,912(1,048,576)   fp32 [NN,DD]
//  extras: KXThi/lo, XbufA/B, Xhi/lo, athi/lo, weight splits, CSR machinery
// ---------------------------------------------------------------------------
extern "C" void kernel_launch(void* const* d_in, const int* in_sizes, int n_in,
                              void* d_out, int out_size, void* d_ws, size_t ws_size,
                              hipStream_t stream)
{
    const float* X0 = (const float*)d_in[0];
    const float* Kw = (const float*)d_in[1];
    const float* Vw = (const float*)d_in[2];
    const float* W1 = (const float*)d_in[3];
    const float* b1 = (const float*)d_in[4];
    const float* W2 = (const float*)d_in[5];
    const float* b2 = (const float*)d_in[6];
    float* out = (float*)d_out;

    float* R0    = (float*)d_ws;
    float* Sh    = R0;                       // 4,194,304 (aliased with Yt)
    float* Yt    = R0;
    u16*   ff1hi = (u16*)(R0 + 4194304);
    u16*   ff1lo = (u16*)(R0 + 6291456);
    float* Cpart = R0 + 8388608;             // 4,194,304
    float* attnT = R0 + 12582912;            // 1,048,576

    float* ext = R0 + 13631488;
    u16* KXThi = (u16*)ext;                  // 262,144 words
    u16* KXTlo = (u16*)(ext + 262144);
    float* XbufA = ext + 524288;             // 1,048,576
    float* XbufB = ext + 1572864;            // 1,048,576
    u16* Xhi  = (u16*)(ext + 2621440);       // 524,288 words
    u16* Xlo  = (u16*)(ext + 3145728);
    u16* athi = (u16*)(ext + 3670016);
    u16* atlo = (u16*)(ext + 4194304);
    u16* Khi  = (u16*)(ext + 4718592);       // 65,536 words
    u16* Klo  = (u16*)(ext + 4784128);
    u16* Vhi  = (u16*)(ext + 4849664);       // 524,288 words
    u16* Vlo  = (u16*)(ext + 5373952);
    u16* W1hi = (u16*)(ext + 5898240);
    u16* W1lo = (u16*)(ext + 6422528);
    u16* W2hi = (u16*)(ext + 6946816);
    u16* W2lo = (u16*)(ext + 7471104);
    float* wrecip = ext + 7995392;           // 8,192
    unsigned int* entries = (unsigned int*)(ext + 8003584);  // 131,072
    unsigned int* csr     = (unsigned int*)(ext + 8134656);  // 131,072
    int* colOff   = (int*)(ext + 8265728);   // 2,112
    int* cursor   = (int*)(ext + 8267840);   // 2,048
    int* cntM     = (int*)(ext + 8269888);   // 2,048
    int* counters = (int*)(ext + 8271936);   // 64

    zero_k<<<dim3(NN / 256), 256, 0, stream>>>(cntM, counters);

    // XT0 = X0^T [N, D]; split to bf16 hi/lo
    transpose_k<<<dim3(NN / 32, DD / 32), 256, 0, stream>>>(X0, XbufA, DD, NN);
    split_k<<<dim3(1024), 256, 0, stream>>>(XbufA, Xhi, Xlo);

    float* Xc = XbufA;
    for (int li = 0; li < LL; li++) {
        float* Xn = (li & 1) ? XbufA : XbufB;

        // 0) split this layer's weights to bf16 hi/lo
        splitw_k<<<dim3(3200), 256, 0, stream>>>(
            Kw + (long)li * 131072, Vw + (long)li * 1048576,
            W1 + (long)li * 1048576, W2 + (long)li * 1048576,
            Khi, Klo, Vhi, Vlo, W1hi, W1lo, W2hi, W2lo);

        // 1) KXT[n][hq] = XT @ Kw^T   [2048, 256], K=512 -> hi/lo only
        mgemm_k<0, 0, 0, 1><<<dim3(2, 16, 1), 256, 0, stream>>>(
            Xhi, Xlo, Khi, Klo, nullptr, KXThi, KXTlo, nullptr,
            NN, HH * QQ, DD, DD, DD, HH * QQ, 0, 0, 0);

        // 2+3) per head: S_h = KXT_h @ KXT_h^T (fp32), then mask extract
        for (int h = 0; h < HH; h++) {
            mgemm_k<0, 0, 1, 0><<<dim3(16, 16, 1), 256, 0, stream>>>(
                KXThi + h * QQ, KXTlo + h * QQ, KXThi + h * QQ, KXTlo + h * QQ,
                Sh, nullptr, nullptr, nullptr,
                NN, NN, QQ, HH * QQ, HH * QQ, NN, 0, 0, 0);
            extract_k<<<dim3(NN / 4), 256, 0, stream>>>(
                Sh, wrecip, entries, counters + li, cntM, h * NN);
        }
        scan_k<<<dim3(1), 256, 0, stream>>>(cntM, colOff, cursor);
        scatter_k<<<dim3(64), 256, 0, stream>>>(entries, counters + li, cursor, csr);

        // 4) Yt_h = XT @ V_h^T  [NN, DD] fp32, batch H (overwrites dead Sh)
        mgemm_k<0, 0, 1, 0><<<dim3(4, 16, HH), 256, 0, stream>>>(
            Xhi, Xlo, Vhi, Vlo, Yt, nullptr, nullptr, nullptr,
            NN, DD, DD, DD, DD, DD, 0, (long)DD * DD, (long)NN * DD);

        // 5) attnT = XT + sparse combine; then split for FF1 input
        initattn_k<<<dim3(NN * DD / 4 / 256), 256, 0, stream>>>(Xc, attnT);
        apply_k<<<dim3(APPLY_BLOCKS), 256, 0, stream>>>(csr, colOff, wrecip, Yt, attnT);
        split_k<<<dim3(1024), 256, 0, stream>>>(attnT, athi, atlo);

        // 6) ff1 = relu(attnT @ W1^T + b1)  [NN, DFF] -> hi/lo only
        mgemm_k<1, 1, 0, 1><<<dim3(16, 16, 1), 256, 0, stream>>>(
            athi, atlo, W1hi, W1lo, nullptr, ff1hi, ff1lo,
            b1 + (long)li * DFFC,
            NN, DFFC, DD, DD, DD, DFFC, 0, 0, 0);

        // 7) FF2 split-K=4: Cpart[s] = ff1[:, s*512..] @ W2[:, s*512..]^T
        mgemm_k<0, 0, 1, 0><<<dim3(4, 16, 4), 256, 0, stream>>>(
            ff1hi, ff1lo, W2hi, W2lo, Cpart, nullptr, nullptr, nullptr,
            NN, DD, 512, DFFC, DFFC, DD, 512, 512, (long)NN * DD);
        ff2red_k<<<dim3(1024), 256, 0, stream>>>(
            Cpart, b2 + (long)li * DD, attnT, Xn, Xhi, Xlo);

        Xc = Xn;
    }

    // out = XT_final^T  [D, N]
    transpose_k<<<dim3(DD / 32, NN / 32), 256, 0, stream>>>(Xc, out, NN, DD);
}

// Round 7
// 3245.878 us; speedup vs baseline: 3.5901x; 1.0642x over previous
//
#include <hip/hip_runtime.h>

// Problem constants
#define LL   8
#define HH   4
#define QQ   64
#define DD   512
#define NN   2048
#define DFFC 2048
#define ENTRY_CAP (1 << 17)
#define CHUNK 8
#define APPLY_BLOCKS 2048

typedef short     bf16x8 __attribute__((ext_vector_type(8)));  // 8 bf16 = 4 VGPR
typedef float     f32x4  __attribute__((ext_vector_type(4)));  // MFMA C/D frag
typedef unsigned short u16;

// fp32 -> (hi, lo) bf16 split, RNE. x ~= hi + lo with ~16-bit mantissa coverage.
__device__ inline void splitf(float v, u16& h, u16& l)
{
    unsigned u  = __float_as_uint(v);
    unsigned uh = u + (0x7FFFu + ((u >> 16) & 1u));
    h = (u16)(uh >> 16);
    float fh = __uint_as_float(((unsigned)h) << 16);
    float r  = v - fh;
    unsigned ur = __float_as_uint(r);
    unsigned ul = ur + (0x7FFFu + ((ur >> 16) & 1u));
    l = (u16)(ul >> 16);
}

// ---------------------------------------------------------------------------
// Split-bf16 MFMA GEMM (NT): C[M,N] = A[M,K] @ B[N,K]^T as hi*hi+hi*lo+lo*hi
// (fp32 accumulate; rel err ~2^-17). Block 256 thr = 4 waves (2x2), block
// tile 128x128, wave tile 64x64 = 4x4 mfma_f32_16x16x32_bf16 frags. Direct
// global->VGPR fragment loads (both operands k-contiguous, 16B/lane).
// (unchanged from R6-passing code)
// ---------------------------------------------------------------------------
template <int BIAS, int RELU, int WF32, int WSPLIT>
__global__ __launch_bounds__(256) void mgemm_k(
    const u16* __restrict__ Ahi, const u16* __restrict__ Alo,
    const u16* __restrict__ Bhi, const u16* __restrict__ Blo,
    float* __restrict__ C, u16* __restrict__ Chi, u16* __restrict__ Clo,
    const float* __restrict__ bias,
    int M, int N, int K, int lda, int ldb, int ldc,
    long sAoff, long sBoff, long sCoff)
{
    const int bz = blockIdx.z;
    Ahi += bz * sAoff;  Alo += bz * sAoff;
    Bhi += bz * sBoff;  Blo += bz * sBoff;
    const long cOff = (long)bz * sCoff;

    const int tid  = threadIdx.x;
    const int wave = tid >> 6, lane = tid & 63;
    const int quad = lane >> 4, l15 = lane & 15;
    const int wy = wave >> 1, wx = wave & 1;
    const int mBase = blockIdx.y * 128 + wy * 64;
    const int nBase = blockIdx.x * 128 + wx * 64;

    f32x4 acc[4][4];
#pragma unroll
    for (int i = 0; i < 4; i++)
#pragma unroll
        for (int j = 0; j < 4; j++)
            acc[i][j] = (f32x4){0.f, 0.f, 0.f, 0.f};

    for (int k0 = 0; k0 < K; k0 += 32) {
        const int kk = k0 + quad * 8;
        bf16x8 ah[4], al[4], bh[4], bl[4];
#pragma unroll
        for (int i = 0; i < 4; i++) {
            long ar = (long)(mBase + i * 16 + l15) * lda + kk;
            ah[i] = *(const bf16x8*)(Ahi + ar);
            al[i] = *(const bf16x8*)(Alo + ar);
            long br = (long)(nBase + i * 16 + l15) * ldb + kk;
            bh[i] = *(const bf16x8*)(Bhi + br);
            bl[i] = *(const bf16x8*)(Blo + br);
        }
#pragma unroll
        for (int i = 0; i < 4; i++)
#pragma unroll
            for (int j = 0; j < 4; j++) {
                acc[i][j] = __builtin_amdgcn_mfma_f32_16x16x32_bf16(ah[i], bh[j], acc[i][j], 0, 0, 0);
                acc[i][j] = __builtin_amdgcn_mfma_f32_16x16x32_bf16(ah[i], bl[j], acc[i][j], 0, 0, 0);
                acc[i][j] = __builtin_amdgcn_mfma_f32_16x16x32_bf16(al[i], bh[j], acc[i][j], 0, 0, 0);
            }
    }

#pragma unroll
    for (int i = 0; i < 4; i++) {
#pragma unroll
        for (int j = 0; j < 4; j++) {
            const int n = nBase + j * 16 + l15;
            const float bv = BIAS ? bias[n] : 0.0f;
#pragma unroll
            for (int r = 0; r < 4; r++) {
                const int m = mBase + i * 16 + quad * 4 + r;
                float v = acc[i][j][r] + bv;
                if (RELU) v = fmaxf(v, 0.0f);
                const long o = cOff + (long)m * ldc + n;
                if (WF32) C[o] = v;
                if (WSPLIT) {
                    u16 h, l;
                    splitf(v, h, l);
                    Chi[o] = h;
                    Clo[o] = l;
                }
            }
        }
    }
}

// ---------------------------------------------------------------------------
// split: fp32 array -> hi/lo bf16 arrays (vec4).
// ---------------------------------------------------------------------------
__global__ __launch_bounds__(256) void split_k(
    const float* __restrict__ src, u16* __restrict__ hi, u16* __restrict__ lo)
{
    int i = blockIdx.x * 256 + threadIdx.x;
    float4 v = ((const float4*)src)[i];
    ushort4 hv, lv;
    splitf(v.x, hv.x, lv.x);
    splitf(v.y, hv.y, lv.y);
    splitf(v.z, hv.z, lv.z);
    splitf(v.w, hv.w, lv.w);
    ((ushort4*)hi)[i] = hv;
    ((ushort4*)lo)[i] = lv;
}

// ---------------------------------------------------------------------------
// splitw: per-layer weight split (K | V | W1 | W2) in one launch.
// ---------------------------------------------------------------------------
__global__ __launch_bounds__(256) void splitw_k(
    const float* __restrict__ K_, const float* __restrict__ V_,
    const float* __restrict__ W1_, const float* __restrict__ W2_,
    u16* __restrict__ Khi, u16* __restrict__ Klo,
    u16* __restrict__ Vhi, u16* __restrict__ Vlo,
    u16* __restrict__ W1hi, u16* __restrict__ W1lo,
    u16* __restrict__ W2hi, u16* __restrict__ W2lo)
{
    int i = blockIdx.x * 256 + threadIdx.x;
    const float* s;
    u16 *h, *l;
    int off;
    if (i < 32768)       { s = K_;  h = Khi;  l = Klo;  off = i; }
    else if (i < 294912) { s = V_;  h = Vhi;  l = Vlo;  off = i - 32768; }
    else if (i < 557056) { s = W1_; h = W1hi; l = W1lo; off = i - 294912; }
    else                 { s = W2_; h = W2hi; l = W2lo; off = i - 557056; }
    float4 v = ((const float4*)s)[off];
    ushort4 hv, lv;
    splitf(v.x, hv.x, lv.x);
    splitf(v.y, hv.y, lv.y);
    splitf(v.z, hv.z, lv.z);
    splitf(v.w, hv.w, lv.w);
    ((ushort4*)h)[off] = hv;
    ((ushort4*)l)[off] = lv;
}

// ---------------------------------------------------------------------------
// zero: reset LL per-layer flat counters (every call; ws is re-poisoned).
// ---------------------------------------------------------------------------
__global__ void zero_k(int* __restrict__ counters)
{
    if (threadIdx.x < LL) counters[threadIdx.x] = 0;
}

// ---------------------------------------------------------------------------
// extract: one wave per score row n of per-head Sh [NN,NN]. Emits wrecip +
// flat packed entries (row<<11|m). Flat-counter atomic is WAVE-AGGREGATED:
// one atomicAdd per hit-ballot, lanes take base+rank (kills same-address
// contention that cost scatter_k 91us in R6).
// ---------------------------------------------------------------------------
__global__ __launch_bounds__(256) void extract_k(
    const float* __restrict__ Sh, float* __restrict__ wrecip,
    unsigned int* __restrict__ entries, int* __restrict__ counter, int rowOff)
{
    int n = blockIdx.x * 4 + (threadIdx.x >> 6);
    int lane = threadIdx.x & 63;
    const float* r = Sh + (long)n * NN;
    const int row = rowOff + n;

    float mx = -3.402823466e38f;
    for (int m = lane; m < NN; m += 64) mx = fmaxf(mx, r[m]);
#pragma unroll
    for (int off = 32; off; off >>= 1) mx = fmaxf(mx, __shfl_xor(mx, off, 64));

    float thr = mx - 0.5f;
    bool active = fabsf(mx) > 0.5f;
    int cnt = 0;
    for (int m = lane; m < NN; m += 64) {
        bool hit = (r[m] >= thr);
        cnt += hit ? 1 : 0;
        if (active && hit) {
            // active lanes here == hit lanes of this iteration
            unsigned long long mask = __ballot(1);
            int nl   = __popcll(mask);
            int rank = __popcll(mask & ((1ull << lane) - 1ull));
            int base = 0;
            if (rank == 0) base = atomicAdd(counter, nl);
            base = __builtin_amdgcn_readfirstlane(base);
            unsigned pos = (unsigned)(base + rank);
            if (pos < ENTRY_CAP)
                entries[pos] = ((unsigned)row << 11) | (unsigned)m;
        }
    }
#pragma unroll
    for (int off = 32; off; off >>= 1) cnt += __shfl_xor(cnt, off, 64);

    if (lane == 0)
        wrecip[row] = active ? 1.0f / fmaxf((float)cnt, 1.0f) : 0.0f;
}

// ---------------------------------------------------------------------------
// buildcsr: single block. LDS histogram of entry columns -> exclusive scan
// -> colOff[2049] -> scatter entries into column-sorted csr via LDS cursors.
// Replaces R6's scan_k + scatter_k; LDS same-address atomics are ~1-2cyc vs
// ~60cyc contended L2 atomics.
// ---------------------------------------------------------------------------
__global__ __launch_bounds__(256) void buildcsr_k(
    const unsigned int* __restrict__ entries, const int* __restrict__ counter,
    unsigned int* __restrict__ csr, int* __restrict__ colOff)
{
    __shared__ int hist[NN];    // histogram, then reused as cursor
    __shared__ int part[256];
    const int t = threadIdx.x;
    int cnt = *counter;
    if (cnt > ENTRY_CAP) cnt = ENTRY_CAP;

    for (int i = t; i < NN; i += 256) hist[i] = 0;
    __syncthreads();
    for (int i = t; i < cnt; i += 256)
        atomicAdd(&hist[entries[i] & 2047], 1);
    __syncthreads();

    // exclusive scan over 2048: 8 per thread + Hillis-Steele over partials
    int e[8];
    int s = 0;
#pragma unroll
    for (int i = 0; i < 8; i++) { e[i] = s; s += hist[t * 8 + i]; }
    part[t] = s;
    __syncthreads();
    for (int off = 1; off < 256; off <<= 1) {
        int x = (t >= off) ? part[t - off] : 0;
        __syncthreads();
        part[t] += x;
        __syncthreads();
    }
    int base = (t > 0) ? part[t - 1] : 0;
    int my[8];
#pragma unroll
    for (int i = 0; i < 8; i++) my[i] = base + e[i];
#pragma unroll
    for (int i = 0; i < 8; i++) colOff[t * 8 + i] = my[i];
    if (t == 255) colOff[NN] = part[255];
    __syncthreads();               // everyone done reading hist as histogram
#pragma unroll
    for (int i = 0; i < 8; i++) hist[t * 8 + i] = my[i];   // cursor init
    __syncthreads();

    for (int i = t; i < cnt; i += 256) {
        unsigned v = entries[i];
        int slot = atomicAdd(&hist[v & 2047], 1);
        csr[slot] = v;
    }
}

// ---------------------------------------------------------------------------
// initattn: attnT = X (residual base), float4 copy.
// ---------------------------------------------------------------------------
__global__ __launch_bounds__(256) void initattn_k(
    const float* __restrict__ X, float* __restrict__ attnT)
{
    long i = (long)blockIdx.x * 256 + threadIdx.x;
    ((float4*)attnT)[i] = ((const float4*)X)[i];
}

// ---------------------------------------------------------------------------
// apply: entry-parallel over column-sorted CSR, CHUNK entries per block,
// register-accumulate per column-run, one atomicAdd set per run. (R5-proven)
// ---------------------------------------------------------------------------
__global__ __launch_bounds__(256) void apply_k(
    const unsigned int* __restrict__ csr, const int* __restrict__ colOff,
    const float* __restrict__ wrecip, const float* __restrict__ Yt,
    float* __restrict__ attnT)
{
    const int total = colOff[NN];
    const int tid = threadIdx.x;

    for (int base = blockIdx.x * CHUNK; base < total;
         base += gridDim.x * CHUNK) {
        int end = base + CHUNK;
        if (end > total) end = total;

        float a0 = 0.0f, a1 = 0.0f;
        int curM = -1;
        for (int e = base; e < end; e++) {
            unsigned v = csr[e];
            int m = v & 2047;
            int row = (int)(v >> 11);
            if (m != curM) {
                if (curM >= 0) {
                    atomicAdd(&attnT[(long)curM * DD + tid], a0);
                    atomicAdd(&attnT[(long)curM * DD + tid + 256], a1);
                }
                curM = m;
                a0 = a1 = 0.0f;
            }
            float w = wrecip[row];
            const float* y = Yt + (long)row * DD;
            a0 += w * y[tid];
            a1 += w * y[tid + 256];
        }
        if (curM >= 0) {
            atomicAdd(&attnT[(long)curM * DD + tid], a0);
            atomicAdd(&attnT[(long)curM * DD + tid + 256], a1);
        }
    }
}

// ---------------------------------------------------------------------------
// ff2red: Xn = sum_{s<4} Cpart[s] + b2(col) + attnT; write fp32 + hi/lo.
// ---------------------------------------------------------------------------
__global__ __launch_bounds__(256) void ff2red_k(
    const float* __restrict__ Cpart, const float* __restrict__ b2,
    const float* __restrict__ attnT, float* __restrict__ Xn,
    u16* __restrict__ Xhi, u16* __restrict__ Xlo)
{
    int i = blockIdx.x * 256 + threadIdx.x;      // vec4 index
    float4 v0 = ((const float4*)(Cpart))[i];
    float4 v1 = ((const float4*)(Cpart + 1048576))[i];
    float4 v2 = ((const float4*)(Cpart + 2097152))[i];
    float4 v3 = ((const float4*)(Cpart + 3145728))[i];
    float4 bv = ((const float4*)b2)[i & 127];
    float4 rv = ((const float4*)attnT)[i];
    float4 o;
    o.x = v0.x + v1.x + v2.x + v3.x + bv.x + rv.x;
    o.y = v0.y + v1.y + v2.y + v3.y + bv.y + rv.y;
    o.z = v0.z + v1.z + v2.z + v3.z + bv.z + rv.z;
    o.w = v0.w + v1.w + v2.w + v3.w + bv.w + rv.w;
    ((float4*)Xn)[i] = o;
    ushort4 hv, lv;
    splitf(o.x, hv.x, lv.x);
    splitf(o.y, hv.y, lv.y);
    splitf(o.z, hv.z, lv.z);
    splitf(o.w, hv.w, lv.w);
    ((ushort4*)Xhi)[i] = hv;
    ((ushort4*)Xlo)[i] = lv;
}

// ---------------------------------------------------------------------------
// transpose: src [R,C] -> dst [C,R]. 32x32 LDS tiles.
// ---------------------------------------------------------------------------
__global__ __launch_bounds__(256) void transpose_k(
    const float* __restrict__ src, float* __restrict__ dst, int R, int C)
{
    __shared__ float t[32][33];
    int tx = threadIdx.x & 31, ty = threadIdx.x >> 5;
    int c0 = blockIdx.x * 32, r0 = blockIdx.y * 32;
#pragma unroll
    for (int k = 0; k < 4; k++)
        t[ty + 8 * k][tx] = src[(long)(r0 + ty + 8 * k) * C + c0 + tx];
    __syncthreads();
#pragma unroll
    for (int k = 0; k < 4; k++)
        dst[(long)(c0 + ty + 8 * k) * R + r0 + tx] = t[tx][ty + 8 * k];
}

// ---------------------------------------------------------------------------
// Workspace (4-byte words), ~87 MB total (< proven 94.4 MB). Same layout as
// R6; cntM/cursor retired (buildcsr uses LDS).
// ---------------------------------------------------------------------------
extern "C" void kernel_launch(void* const* d_in, const int* in_sizes, int n_in,
                              void* d_out, int out_size, void* d_ws, size_t ws_size,
                              hipStream_t stream)
{
    const float* X0 = (const float*)d_in[0];
    const float* Kw = (const float*)d_in[1];
    const float* Vw = (const float*)d_in[2];
    const float* W1 = (const float*)d_in[3];
    const float* b1 = (const float*)d_in[4];
    const float* W2 = (const float*)d_in[5];
    const float* b2 = (const float*)d_in[6];
    float* out = (float*)d_out;

    float* R0    = (float*)d_ws;
    float* Sh    = R0;                       // 4,194,304 (aliased with Yt)
    float* Yt    = R0;
    u16*   ff1hi = (u16*)(R0 + 4194304);
    u16*   ff1lo = (u16*)(R0 + 6291456);
    float* Cpart = R0 + 8388608;             // 4,194,304
    float* attnT = R0 + 12582912;            // 1,048,576

    float* ext = R0 + 13631488;
    u16* KXThi = (u16*)ext;                  // 262,144 words
    u16* KXTlo = (u16*)(ext + 262144);
    float* XbufA = ext + 524288;             // 1,048,576
    float* XbufB = ext + 1572864;            // 1,048,576
    u16* Xhi  = (u16*)(ext + 2621440);       // 524,288 words
    u16* Xlo  = (u16*)(ext + 3145728);
    u16* athi = (u16*)(ext + 3670016);
    u16* atlo = (u16*)(ext + 4194304);
    u16* Khi  = (u16*)(ext + 4718592);       // 65,536 words
    u16* Klo  = (u16*)(ext + 4784128);
    u16* Vhi  = (u16*)(ext + 4849664);       // 524,288 words
    u16* Vlo  = (u16*)(ext + 5373952);
    u16* W1hi = (u16*)(ext + 5898240);
    u16* W1lo = (u16*)(ext + 6422528);
    u16* W2hi = (u16*)(ext + 6946816);
    u16* W2lo = (u16*)(ext + 7471104);
    float* wrecip = ext + 7995392;           // 8,192
    unsigned int* entries = (unsigned int*)(ext + 8003584);  // 131,072
    unsigned int* csr     = (unsigned int*)(ext + 8134656);  // 131,072
    int* colOff   = (int*)(ext + 8265728);   // 2,112
    int* counters = (int*)(ext + 8267840);   // 64

    zero_k<<<1, 64, 0, stream>>>(counters);

    // XT0 = X0^T [N, D]; split to bf16 hi/lo
    transpose_k<<<dim3(NN / 32, DD / 32), 256, 0, stream>>>(X0, XbufA, DD, NN);
    split_k<<<dim3(1024), 256, 0, stream>>>(XbufA, Xhi, Xlo);

    float* Xc = XbufA;
    for (int li = 0; li < LL; li++) {
        float* Xn = (li & 1) ? XbufA : XbufB;

        // 0) split this layer's weights to bf16 hi/lo
        splitw_k<<<dim3(3200), 256, 0, stream>>>(
            Kw + (long)li * 131072, Vw + (long)li * 1048576,
            W1 + (long)li * 1048576, W2 + (long)li * 1048576,
            Khi, Klo, Vhi, Vlo, W1hi, W1lo, W2hi, W2lo);

        // 1) KXT[n][hq] = XT @ Kw^T   [2048, 256], K=512 -> hi/lo only
        mgemm_k<0, 0, 0, 1><<<dim3(2, 16, 1), 256, 0, stream>>>(
            Xhi, Xlo, Khi, Klo, nullptr, KXThi, KXTlo, nullptr,
            NN, HH * QQ, DD, DD, DD, HH * QQ, 0, 0, 0);

        // 2+3) per head: S_h = KXT_h @ KXT_h^T (fp32), then mask extract
        for (int h = 0; h < HH; h++) {
            mgemm_k<0, 0, 1, 0><<<dim3(16, 16, 1), 256, 0, stream>>>(
                KXThi + h * QQ, KXTlo + h * QQ, KXThi + h * QQ, KXTlo + h * QQ,
                Sh, nullptr, nullptr, nullptr,
                NN, NN, QQ, HH * QQ, HH * QQ, NN, 0, 0, 0);
            extract_k<<<dim3(NN / 4), 256, 0, stream>>>(
                Sh, wrecip, entries, counters + li, h * NN);
        }
        buildcsr_k<<<dim3(1), 256, 0, stream>>>(entries, counters + li, csr, colOff);

        // 4) Yt_h = XT @ V_h^T  [NN, DD] fp32, batch H (overwrites dead Sh)
        mgemm_k<0, 0, 1, 0><<<dim3(4, 16, HH), 256, 0, stream>>>(
            Xhi, Xlo, Vhi, Vlo, Yt, nullptr, nullptr, nullptr,
            NN, DD, DD, DD, DD, DD, 0, (long)DD * DD, (long)NN * DD);

        // 5) attnT = XT + sparse combine; then split for FF1 input
        initattn_k<<<dim3(NN * DD / 4 / 256), 256, 0, stream>>>(Xc, attnT);
        apply_k<<<dim3(APPLY_BLOCKS), 256, 0, stream>>>(csr, colOff, wrecip, Yt, attnT);
        split_k<<<dim3(1024), 256, 0, stream>>>(attnT, athi, atlo);

        // 6) ff1 = relu(attnT @ W1^T + b1)  [NN, DFF] -> hi/lo only
        mgemm_k<1, 1, 0, 1><<<dim3(16, 16, 1), 256, 0, stream>>>(
            athi, atlo, W1hi, W1lo, nullptr, ff1hi, ff1lo,
            b1 + (long)li * DFFC,
            NN, DFFC, DD, DD, DD, DFFC, 0, 0, 0);

        // 7) FF2 split-K=4: Cpart[s] = ff1[:, s*512..] @ W2[:, s*512..]^T
        mgemm_k<0, 0, 1, 0><<<dim3(4, 16, 4), 256, 0, stream>>>(
            ff1hi, ff1lo, W2hi, W2lo, Cpart, nullptr, nullptr, nullptr,
            NN, DD, 512, DFFC, DFFC, DD, 512, 512, (long)NN * DD);
        ff2red_k<<<dim3(1024), 256, 0, stream>>>(
            Cpart, b2 + (long)li * DD, attnT, Xn, Xhi, Xlo);

        Xc = Xn;
    }

    // out = XT_final^T  [D, N]
    transpose_k<<<dim3(DD / 32, NN / 32), 256, 0, stream>>>(Xc, out, NN, DD);
}

// Round 8
// 2355.172 us; speedup vs baseline: 4.9479x; 1.3782x over previous
//
#include <hip/hip_runtime.h>

// Problem constants
#define LL   8
#define HH   4
#define QQ   64
#define DD   512
#define NN   2048
#define DFFC 2048
#define ENTRY_CAP (1 << 17)
#define CHUNK 8
#define APPLY_BLOCKS 2048

typedef short     bf16x8 __attribute__((ext_vector_type(8)));  // 8 bf16 = 4 VGPR
typedef float     f32x4  __attribute__((ext_vector_type(4)));  // MFMA C/D frag
typedef unsigned short u16;

// fp32 -> (hi, lo) bf16 split, RNE. x ~= hi + lo with ~16-bit mantissa coverage.
__device__ inline void splitf(float v, u16& h, u16& l)
{
    unsigned u  = __float_as_uint(v);
    unsigned uh = u + (0x7FFFu + ((u >> 16) & 1u));
    h = (u16)(uh >> 16);
    float fh = __uint_as_float(((unsigned)h) << 16);
    float r  = v - fh;
    unsigned ur = __float_as_uint(r);
    unsigned ul = ur + (0x7FFFu + ((ur >> 16) & 1u));
    l = (u16)(ul >> 16);
}

// Monotone fp32 <-> uint mapping for atomicMax on floats (no NaNs in data).
__device__ inline unsigned mapf(float f)
{
    unsigned u = __float_as_uint(f);
    return (u >> 31) ? ~u : (u | 0x80000000u);
}
__device__ inline float unmapf(unsigned u)
{
    return (u >> 31) ? __uint_as_float(u ^ 0x80000000u) : __uint_as_float(~u);
}

// ---------------------------------------------------------------------------
// Split-bf16 MFMA GEMM (NT): C[M,N] = A[M,K] @ B[N,K]^T as hi*hi+hi*lo+lo*hi
// (fp32 accumulate). Block 256 thr = 4 waves (2x2), block tile 128x128, wave
// tile 64x64 = 4x4 mfma_f32_16x16x32_bf16 frags. Direct global->VGPR loads.
// (unchanged from R6/R7-passing code)
// ---------------------------------------------------------------------------
template <int BIAS, int RELU, int WF32, int WSPLIT>
__global__ __launch_bounds__(256) void mgemm_k(
    const u16* __restrict__ Ahi, const u16* __restrict__ Alo,
    const u16* __restrict__ Bhi, const u16* __restrict__ Blo,
    float* __restrict__ C, u16* __restrict__ Chi, u16* __restrict__ Clo,
    const float* __restrict__ bias,
    int M, int N, int K, int lda, int ldb, int ldc,
    long sAoff, long sBoff, long sCoff)
{
    const int bz = blockIdx.z;
    Ahi += bz * sAoff;  Alo += bz * sAoff;
    Bhi += bz * sBoff;  Blo += bz * sBoff;
    const long cOff = (long)bz * sCoff;

    const int tid  = threadIdx.x;
    const int wave = tid >> 6, lane = tid & 63;
    const int quad = lane >> 4, l15 = lane & 15;
    const int wy = wave >> 1, wx = wave & 1;
    const int mBase = blockIdx.y * 128 + wy * 64;
    const int nBase = blockIdx.x * 128 + wx * 64;

    f32x4 acc[4][4];
#pragma unroll
    for (int i = 0; i < 4; i++)
#pragma unroll
        for (int j = 0; j < 4; j++)
            acc[i][j] = (f32x4){0.f, 0.f, 0.f, 0.f};

    for (int k0 = 0; k0 < K; k0 += 32) {
        const int kk = k0 + quad * 8;
        bf16x8 ah[4], al[4], bh[4], bl[4];
#pragma unroll
        for (int i = 0; i < 4; i++) {
            long ar = (long)(mBase + i * 16 + l15) * lda + kk;
            ah[i] = *(const bf16x8*)(Ahi + ar);
            al[i] = *(const bf16x8*)(Alo + ar);
            long br = (long)(nBase + i * 16 + l15) * ldb + kk;
            bh[i] = *(const bf16x8*)(Bhi + br);
            bl[i] = *(const bf16x8*)(Blo + br);
        }
#pragma unroll
        for (int i = 0; i < 4; i++)
#pragma unroll
            for (int j = 0; j < 4; j++) {
                acc[i][j] = __builtin_amdgcn_mfma_f32_16x16x32_bf16(ah[i], bh[j], acc[i][j], 0, 0, 0);
                acc[i][j] = __builtin_amdgcn_mfma_f32_16x16x32_bf16(ah[i], bl[j], acc[i][j], 0, 0, 0);
                acc[i][j] = __builtin_amdgcn_mfma_f32_16x16x32_bf16(al[i], bh[j], acc[i][j], 0, 0, 0);
            }
    }

#pragma unroll
    for (int i = 0; i < 4; i++) {
#pragma unroll
        for (int j = 0; j < 4; j++) {
            const int n = nBase + j * 16 + l15;
            const float bv = BIAS ? bias[n] : 0.0f;
#pragma unroll
            for (int r = 0; r < 4; r++) {
                const int m = mBase + i * 16 + quad * 4 + r;
                float v = acc[i][j][r] + bv;
                if (RELU) v = fmaxf(v, 0.0f);
                const long o = cOff + (long)m * ldc + n;
                if (WF32) C[o] = v;
                if (WSPLIT) {
                    u16 h, l;
                    splitf(v, h, l);
                    Chi[o] = h;
                    Clo[o] = l;
                }
            }
        }
    }
}

// ---------------------------------------------------------------------------
// Fused mask path, pass A: per-head Gram tile S = G G^T computed in regs;
// row-max reduced (over j frags, then 16-lane shuffle) -> global atomicMax.
// S is NEVER written to memory. Grid (16,16,HH); A=B=KXT_h, K=QQ.
// ---------------------------------------------------------------------------
__global__ __launch_bounds__(256) void smax_k(
    const u16* __restrict__ Ghi, const u16* __restrict__ Glo,
    unsigned* __restrict__ rowmaxU)
{
    const int h = blockIdx.z;
    const u16* Ah = Ghi + h * QQ;
    const u16* Al = Glo + h * QQ;
    const int lda = HH * QQ;

    const int tid  = threadIdx.x;
    const int wave = tid >> 6, lane = tid & 63;
    const int quad = lane >> 4, l15 = lane & 15;
    const int wy = wave >> 1, wx = wave & 1;
    const int rB = blockIdx.y * 128 + wy * 64;   // score rows
    const int cB = blockIdx.x * 128 + wx * 64;   // cols

    f32x4 acc[4][4];
#pragma unroll
    for (int i = 0; i < 4; i++)
#pragma unroll
        for (int j = 0; j < 4; j++)
            acc[i][j] = (f32x4){0.f, 0.f, 0.f, 0.f};

    for (int k0 = 0; k0 < QQ; k0 += 32) {
        const int kk = k0 + quad * 8;
        bf16x8 ah[4], al[4], bh[4], bl[4];
#pragma unroll
        for (int i = 0; i < 4; i++) {
            long ar = (long)(rB + i * 16 + l15) * lda + kk;
            ah[i] = *(const bf16x8*)(Ah + ar);
            al[i] = *(const bf16x8*)(Al + ar);
            long br = (long)(cB + i * 16 + l15) * lda + kk;
            bh[i] = *(const bf16x8*)(Ah + br);
            bl[i] = *(const bf16x8*)(Al + br);
        }
#pragma unroll
        for (int i = 0; i < 4; i++)
#pragma unroll
            for (int j = 0; j < 4; j++) {
                acc[i][j] = __builtin_amdgcn_mfma_f32_16x16x32_bf16(ah[i], bh[j], acc[i][j], 0, 0, 0);
                acc[i][j] = __builtin_amdgcn_mfma_f32_16x16x32_bf16(ah[i], bl[j], acc[i][j], 0, 0, 0);
                acc[i][j] = __builtin_amdgcn_mfma_f32_16x16x32_bf16(al[i], bh[j], acc[i][j], 0, 0, 0);
            }
    }

#pragma unroll
    for (int i = 0; i < 4; i++)
#pragma unroll
        for (int r = 0; r < 4; r++) {
            float mx = acc[i][0][r];
#pragma unroll
            for (int j = 1; j < 4; j++) mx = fmaxf(mx, acc[i][j][r]);
#pragma unroll
            for (int off = 1; off < 16; off <<= 1)
                mx = fmaxf(mx, __shfl_xor(mx, off, 64));
            if (l15 == 0)
                atomicMax(&rowmaxU[h * NN + rB + i * 16 + quad * 4 + r], mapf(mx));
        }
}

// ---------------------------------------------------------------------------
// Fused mask path, pass B: recompute the IDENTICAL S tile (bitwise-same MFMA
// sequence), threshold vs rowmax-0.5 (inactive rows -> +inf), count hits per
// row (shuffle + atomicAdd) and emit packed entries (wave-aggregated).
// ---------------------------------------------------------------------------
__global__ __launch_bounds__(256) void sextract_k(
    const u16* __restrict__ Ghi, const u16* __restrict__ Glo,
    const unsigned* __restrict__ rowmaxU, int* __restrict__ rowcnt,
    unsigned int* __restrict__ entries, int* __restrict__ counter)
{
    const int h = blockIdx.z;
    const u16* Ah = Ghi + h * QQ;
    const u16* Al = Glo + h * QQ;
    const int lda = HH * QQ;

    const int tid  = threadIdx.x;
    const int wave = tid >> 6, lane = tid & 63;
    const int quad = lane >> 4, l15 = lane & 15;
    const int wy = wave >> 1, wx = wave & 1;
    const int rB = blockIdx.y * 128 + wy * 64;
    const int cB = blockIdx.x * 128 + wx * 64;

    __shared__ float thrS[128];
    if (tid < 128) {
        float mx = unmapf(rowmaxU[h * NN + blockIdx.y * 128 + tid]);
        thrS[tid] = (fabsf(mx) > 0.5f) ? mx - 0.5f : 3.402823466e38f;
    }
    __syncthreads();

    f32x4 acc[4][4];
#pragma unroll
    for (int i = 0; i < 4; i++)
#pragma unroll
        for (int j = 0; j < 4; j++)
            acc[i][j] = (f32x4){0.f, 0.f, 0.f, 0.f};

    for (int k0 = 0; k0 < QQ; k0 += 32) {
        const int kk = k0 + quad * 8;
        bf16x8 ah[4], al[4], bh[4], bl[4];
#pragma unroll
        for (int i = 0; i < 4; i++) {
            long ar = (long)(rB + i * 16 + l15) * lda + kk;
            ah[i] = *(const bf16x8*)(Ah + ar);
            al[i] = *(const bf16x8*)(Al + ar);
            long br = (long)(cB + i * 16 + l15) * lda + kk;
            bh[i] = *(const bf16x8*)(Ah + br);
            bl[i] = *(const bf16x8*)(Al + br);
        }
#pragma unroll
        for (int i = 0; i < 4; i++)
#pragma unroll
            for (int j = 0; j < 4; j++) {
                acc[i][j] = __builtin_amdgcn_mfma_f32_16x16x32_bf16(ah[i], bh[j], acc[i][j], 0, 0, 0);
                acc[i][j] = __builtin_amdgcn_mfma_f32_16x16x32_bf16(ah[i], bl[j], acc[i][j], 0, 0, 0);
                acc[i][j] = __builtin_amdgcn_mfma_f32_16x16x32_bf16(al[i], bh[j], acc[i][j], 0, 0, 0);
            }
    }

#pragma unroll
    for (int i = 0; i < 4; i++) {
#pragma unroll
        for (int r = 0; r < 4; r++) {
            const int lr  = wy * 64 + i * 16 + quad * 4 + r;   // block-local row
            const int row = h * NN + rB + i * 16 + quad * 4 + r;
            const float thr = thrS[lr];

            int c = 0;
#pragma unroll
            for (int j = 0; j < 4; j++) c += (acc[i][j][r] >= thr) ? 1 : 0;
            int cs = c;
#pragma unroll
            for (int off = 1; off < 16; off <<= 1) cs += __shfl_xor(cs, off, 64);
            if (l15 == 0 && cs > 0) atomicAdd(&rowcnt[row], cs);

#pragma unroll
            for (int j = 0; j < 4; j++) {
                if (acc[i][j][r] >= thr) {
                    unsigned long long mb = __ballot(1);
                    int nl   = __popcll(mb);
                    int rank = __popcll(mb & ((1ull << lane) - 1ull));
                    int base = 0;
                    if (rank == 0) base = atomicAdd(counter, nl);
                    base = __builtin_amdgcn_readfirstlane(base);
                    unsigned pos = (unsigned)(base + rank);
                    if (pos < ENTRY_CAP)
                        entries[pos] = ((unsigned)row << 11) |
                                       (unsigned)(cB + j * 16 + l15);
                }
            }
        }
    }
}

// ---------------------------------------------------------------------------
// initrow: zero rowmaxU[8192] and rowcnt[8192] (adjacent) per layer.
// ---------------------------------------------------------------------------
__global__ __launch_bounds__(256) void initrow_k(unsigned* __restrict__ p)
{
    p[blockIdx.x * 256 + threadIdx.x] = 0u;
}

// ---------------------------------------------------------------------------
// wrecip: wrecip[row] = active ? 1/max(cnt,1) : 0.
// ---------------------------------------------------------------------------
__global__ __launch_bounds__(256) void wrecip_k(
    const unsigned* __restrict__ rowmaxU, const int* __restrict__ rowcnt,
    float* __restrict__ wrecip)
{
    int i = blockIdx.x * 256 + threadIdx.x;
    float mx = unmapf(rowmaxU[i]);
    wrecip[i] = (fabsf(mx) > 0.5f) ? 1.0f / fmaxf((float)rowcnt[i], 1.0f) : 0.0f;
}

// ---------------------------------------------------------------------------
// split / splitw / zero / buildcsr / initattn / apply / ff2red / transpose
// (unchanged from R7-passing code)
// ---------------------------------------------------------------------------
__global__ __launch_bounds__(256) void split_k(
    const float* __restrict__ src, u16* __restrict__ hi, u16* __restrict__ lo)
{
    int i = blockIdx.x * 256 + threadIdx.x;
    float4 v = ((const float4*)src)[i];
    ushort4 hv, lv;
    splitf(v.x, hv.x, lv.x);
    splitf(v.y, hv.y, lv.y);
    splitf(v.z, hv.z, lv.z);
    splitf(v.w, hv.w, lv.w);
    ((ushort4*)hi)[i] = hv;
    ((ushort4*)lo)[i] = lv;
}

__global__ __launch_bounds__(256) void splitw_k(
    const float* __restrict__ K_, const float* __restrict__ V_,
    const float* __restrict__ W1_, const float* __restrict__ W2_,
    u16* __restrict__ Khi, u16* __restrict__ Klo,
    u16* __restrict__ Vhi, u16* __restrict__ Vlo,
    u16* __restrict__ W1hi, u16* __restrict__ W1lo,
    u16* __restrict__ W2hi, u16* __restrict__ W2lo)
{
    int i = blockIdx.x * 256 + threadIdx.x;
    const float* s;
    u16 *h, *l;
    int off;
    if (i < 32768)       { s = K_;  h = Khi;  l = Klo;  off = i; }
    else if (i < 294912) { s = V_;  h = Vhi;  l = Vlo;  off = i - 32768; }
    else if (i < 557056) { s = W1_; h = W1hi; l = W1lo; off = i - 294912; }
    else                 { s = W2_; h = W2hi; l = W2lo; off = i - 557056; }
    float4 v = ((const float4*)s)[off];
    ushort4 hv, lv;
    splitf(v.x, hv.x, lv.x);
    splitf(v.y, hv.y, lv.y);
    splitf(v.z, hv.z, lv.z);
    splitf(v.w, hv.w, lv.w);
    ((ushort4*)h)[off] = hv;
    ((ushort4*)l)[off] = lv;
}

__global__ void zero_k(int* __restrict__ counters)
{
    if (threadIdx.x < LL) counters[threadIdx.x] = 0;
}

__global__ __launch_bounds__(256) void buildcsr_k(
    const unsigned int* __restrict__ entries, const int* __restrict__ counter,
    unsigned int* __restrict__ csr, int* __restrict__ colOff)
{
    __shared__ int hist[NN];
    __shared__ int part[256];
    const int t = threadIdx.x;
    int cnt = *counter;
    if (cnt > ENTRY_CAP) cnt = ENTRY_CAP;

    for (int i = t; i < NN; i += 256) hist[i] = 0;
    __syncthreads();
    for (int i = t; i < cnt; i += 256)
        atomicAdd(&hist[entries[i] & 2047], 1);
    __syncthreads();

    int e[8];
    int s = 0;
#pragma unroll
    for (int i = 0; i < 8; i++) { e[i] = s; s += hist[t * 8 + i]; }
    part[t] = s;
    __syncthreads();
    for (int off = 1; off < 256; off <<= 1) {
        int x = (t >= off) ? part[t - off] : 0;
        __syncthreads();
        part[t] += x;
        __syncthreads();
    }
    int base = (t > 0) ? part[t - 1] : 0;
    int my[8];
#pragma unroll
    for (int i = 0; i < 8; i++) my[i] = base + e[i];
#pragma unroll
    for (int i = 0; i < 8; i++) colOff[t * 8 + i] = my[i];
    if (t == 255) colOff[NN] = part[255];
    __syncthreads();
#pragma unroll
    for (int i = 0; i < 8; i++) hist[t * 8 + i] = my[i];
    __syncthreads();

    for (int i = t; i < cnt; i += 256) {
        unsigned v = entries[i];
        int slot = atomicAdd(&hist[v & 2047], 1);
        csr[slot] = v;
    }
}

__global__ __launch_bounds__(256) void initattn_k(
    const float* __restrict__ X, float* __restrict__ attnT)
{
    long i = (long)blockIdx.x * 256 + threadIdx.x;
    ((float4*)attnT)[i] = ((const float4*)X)[i];
}

__global__ __launch_bounds__(256) void apply_k(
    const unsigned int* __restrict__ csr, const int* __restrict__ colOff,
    const float* __restrict__ wrecip, const float* __restrict__ Yt,
    float* __restrict__ attnT)
{
    const int total = colOff[NN];
    const int tid = threadIdx.x;

    for (int base = blockIdx.x * CHUNK; base < total;
         base += gridDim.x * CHUNK) {
        int end = base + CHUNK;
        if (end > total) end = total;

        float a0 = 0.0f, a1 = 0.0f;
        int curM = -1;
        for (int e = base; e < end; e++) {
            unsigned v = csr[e];
            int m = v & 2047;
            int row = (int)(v >> 11);
            if (m != curM) {
                if (curM >= 0) {
                    atomicAdd(&attnT[(long)curM * DD + tid], a0);
                    atomicAdd(&attnT[(long)curM * DD + tid + 256], a1);
                }
                curM = m;
                a0 = a1 = 0.0f;
            }
            float w = wrecip[row];
            const float* y = Yt + (long)row * DD;
            a0 += w * y[tid];
            a1 += w * y[tid + 256];
        }
        if (curM >= 0) {
            atomicAdd(&attnT[(long)curM * DD + tid], a0);
            atomicAdd(&attnT[(long)curM * DD + tid + 256], a1);
        }
    }
}

__global__ __launch_bounds__(256) void ff2red_k(
    const float* __restrict__ Cpart, const float* __restrict__ b2,
    const float* __restrict__ attnT, float* __restrict__ Xn,
    u16* __restrict__ Xhi, u16* __restrict__ Xlo)
{
    int i = blockIdx.x * 256 + threadIdx.x;
    float4 v0 = ((const float4*)(Cpart))[i];
    float4 v1 = ((const float4*)(Cpart + 1048576))[i];
    float4 v2 = ((const float4*)(Cpart + 2097152))[i];
    float4 v3 = ((const float4*)(Cpart + 3145728))[i];
    float4 bv = ((const float4*)b2)[i & 127];
    float4 rv = ((const float4*)attnT)[i];
    float4 o;
    o.x = v0.x + v1.x + v2.x + v3.x + bv.x + rv.x;
    o.y = v0.y + v1.y + v2.y + v3.y + bv.y + rv.y;
    o.z = v0.z + v1.z + v2.z + v3.z + bv.z + rv.z;
    o.w = v0.w + v1.w + v2.w + v3.w + bv.w + rv.w;
    ((float4*)Xn)[i] = o;
    ushort4 hv, lv;
    splitf(o.x, hv.x, lv.x);
    splitf(o.y, hv.y, lv.y);
    splitf(o.z, hv.z, lv.z);
    splitf(o.w, hv.w, lv.w);
    ((ushort4*)Xhi)[i] = hv;
    ((ushort4*)Xlo)[i] = lv;
}

__global__ __launch_bounds__(256) void transpose_k(
    const float* __restrict__ src, float* __restrict__ dst, int R, int C)
{
    __shared__ float t[32][33];
    int tx = threadIdx.x & 31, ty = threadIdx.x >> 5;
    int c0 = blockIdx.x * 32, r0 = blockIdx.y * 32;
#pragma unroll
    for (int k = 0; k < 4; k++)
        t[ty + 8 * k][tx] = src[(long)(r0 + ty + 8 * k) * C + c0 + tx];
    __syncthreads();
#pragma unroll
    for (int k = 0; k < 4; k++)
        dst[(long)(c0 + ty + 8 * k) * R + r0 + tx] = t[tx][ty + 8 * k];
}

// ---------------------------------------------------------------------------
// Workspace (4-byte words), ~87 MB (< proven 94.4 MB). S is no longer
// materialized; Yt still lives at R0. rowmaxU/rowcnt appended after counters.
// ---------------------------------------------------------------------------
extern "C" void kernel_launch(void* const* d_in, const int* in_sizes, int n_in,
                              void* d_out, int out_size, void* d_ws, size_t ws_size,
                              hipStream_t stream)
{
    const float* X0 = (const float*)d_in[0];
    const float* Kw = (const float*)d_in[1];
    const float* Vw = (const float*)d_in[2];
    const float* W1 = (const float*)d_in[3];
    const float* b1 = (const float*)d_in[4];
    const float* W2 = (const float*)d_in[5];
    const float* b2 = (const float*)d_in[6];
    float* out = (float*)d_out;

    float* R0    = (float*)d_ws;
    float* Yt    = R0;                       // 4,194,304  [H,NN,DD] fp32
    u16*   ff1hi = (u16*)(R0 + 4194304);
    u16*   ff1lo = (u16*)(R0 + 6291456);
    float* Cpart = R0 + 8388608;             // 4,194,304
    float* attnT = R0 + 12582912;            // 1,048,576

    float* ext = R0 + 13631488;
    u16* KXThi = (u16*)ext;                  // 262,144 words
    u16* KXTlo = (u16*)(ext + 262144);
    float* XbufA = ext + 524288;             // 1,048,576
    float* XbufB = ext + 1572864;            // 1,048,576
    u16* Xhi  = (u16*)(ext + 2621440);       // 524,288 words
    u16* Xlo  = (u16*)(ext + 3145728);
    u16* athi = (u16*)(ext + 3670016);
    u16* atlo = (u16*)(ext + 4194304);
    u16* Khi  = (u16*)(ext + 4718592);       // 65,536 words
    u16* Klo  = (u16*)(ext + 4784128);
    u16* Vhi  = (u16*)(ext + 4849664);       // 524,288 words
    u16* Vlo  = (u16*)(ext + 5373952);
    u16* W1hi = (u16*)(ext + 5898240);
    u16* W1lo = (u16*)(ext + 6422528);
    u16* W2hi = (u16*)(ext + 6946816);
    u16* W2lo = (u16*)(ext + 7471104);
    float* wrecip = ext + 7995392;           // 8,192
    unsigned int* entries = (unsigned int*)(ext + 8003584);  // 131,072
    unsigned int* csr     = (unsigned int*)(ext + 8134656);  // 131,072
    int* colOff   = (int*)(ext + 8265728);   // 2,112
    int* counters = (int*)(ext + 8267840);   // 64
    unsigned* rowmaxU = (unsigned*)(ext + 8267904);  // 8,192
    int* rowcnt   = (int*)(ext + 8276096);   // 8,192 (adjacent to rowmaxU)

    zero_k<<<1, 64, 0, stream>>>(counters);

    // XT0 = X0^T [N, D]; split to bf16 hi/lo
    transpose_k<<<dim3(NN / 32, DD / 32), 256, 0, stream>>>(X0, XbufA, DD, NN);
    split_k<<<dim3(1024), 256, 0, stream>>>(XbufA, Xhi, Xlo);

    float* Xc = XbufA;
    for (int li = 0; li < LL; li++) {
        float* Xn = (li & 1) ? XbufA : XbufB;

        // 0) split this layer's weights to bf16 hi/lo
        splitw_k<<<dim3(3200), 256, 0, stream>>>(
            Kw + (long)li * 131072, Vw + (long)li * 1048576,
            W1 + (long)li * 1048576, W2 + (long)li * 1048576,
            Khi, Klo, Vhi, Vlo, W1hi, W1lo, W2hi, W2lo);

        // 1) KXT[n][hq] = XT @ Kw^T   [2048, 256], K=512 -> hi/lo only
        mgemm_k<0, 0, 0, 1><<<dim3(2, 16, 1), 256, 0, stream>>>(
            Xhi, Xlo, Khi, Klo, nullptr, KXThi, KXTlo, nullptr,
            NN, HH * QQ, DD, DD, DD, HH * QQ, 0, 0, 0);

        // 2) fused mask path: no S materialization
        initrow_k<<<dim3(64), 256, 0, stream>>>(rowmaxU);   // zeroes rowcnt too
        smax_k<<<dim3(16, 16, HH), 256, 0, stream>>>(KXThi, KXTlo, rowmaxU);
        sextract_k<<<dim3(16, 16, HH), 256, 0, stream>>>(
            KXThi, KXTlo, rowmaxU, rowcnt, entries, counters + li);
        wrecip_k<<<dim3(32), 256, 0, stream>>>(rowmaxU, rowcnt, wrecip);
        buildcsr_k<<<dim3(1), 256, 0, stream>>>(entries, counters + li, csr, colOff);

        // 4) Yt_h = XT @ V_h^T  [NN, DD] fp32, batch H
        mgemm_k<0, 0, 1, 0><<<dim3(4, 16, HH), 256, 0, stream>>>(
            Xhi, Xlo, Vhi, Vlo, Yt, nullptr, nullptr, nullptr,
            NN, DD, DD, DD, DD, DD, 0, (long)DD * DD, (long)NN * DD);

        // 5) attnT = XT + sparse combine; then split for FF1 input
        initattn_k<<<dim3(NN * DD / 4 / 256), 256, 0, stream>>>(Xc, attnT);
        apply_k<<<dim3(APPLY_BLOCKS), 256, 0, stream>>>(csr, colOff, wrecip, Yt, attnT);
        split_k<<<dim3(1024), 256, 0, stream>>>(attnT, athi, atlo);

        // 6) ff1 = relu(attnT @ W1^T + b1)  [NN, DFF] -> hi/lo only
        mgemm_k<1, 1, 0, 1><<<dim3(16, 16, 1), 256, 0, stream>>>(
            athi, atlo, W1hi, W1lo, nullptr, ff1hi, ff1lo,
            b1 + (long)li * DFFC,
            NN, DFFC, DD, DD, DD, DFFC, 0, 0, 0);

        // 7) FF2 split-K=4: Cpart[s] = ff1[:, s*512..] @ W2[:, s*512..]^T
        mgemm_k<0, 0, 1, 0><<<dim3(4, 16, 4), 256, 0, stream>>>(
            ff1hi, ff1lo, W2hi, W2lo, Cpart, nullptr, nullptr, nullptr,
            NN, DD, 512, DFFC, DFFC, DD, 512, 512, (long)NN * DD);
        ff2red_k<<<dim3(1024), 256, 0, stream>>>(
            Cpart, b2 + (long)li * DD, attnT, Xn, Xhi, Xlo);

        Xc = Xn;
    }

    // out = XT_final^T  [D, N]
    transpose_k<<<dim3(DD / 32, NN / 32), 256, 0, stream>>>(Xc, out, NN, DD);
}